// Round 1
// baseline (13958.125 us; speedup 1.0000x reference)
//
#include <hip/hip_runtime.h>
#include <math.h>

namespace {

constexpr int B_ = 8, C_ = 512, H_ = 96, W_ = 96;
constexpr int HP = 48, WP = 48, N_ = HP * WP;   // pooled spatial, N=2304
constexpr int KD = 256, VD = 256, OD = 512;
constexpr float EPSV = 1e-5f;

// workspace layout (float offsets)
constexpr size_t OFF_XP  = 0;                                   // [B][C][N]
constexpr size_t OFF_QK  = OFF_XP  + (size_t)B_ * C_ * N_;      // [B][KD][N]
constexpr size_t OFF_VAL = OFF_QK  + (size_t)B_ * KD * N_;      // [B][VD][N]
constexpr size_t OFF_CTX = OFF_VAL + (size_t)B_ * VD * N_;      // [B][VD][N]
constexpr size_t OFF_WF  = OFF_CTX + (size_t)B_ * VD * N_;      // [OD][VD]
constexpr size_t OFF_BF  = OFF_WF  + (size_t)OD * VD;           // [OD]
constexpr size_t OFF_Z   = OFF_XP;                              // reuse xp: [B][OD][N]

} // namespace

// ---------------------------------------------------------------- maxpool 2x2
__global__ void maxpool_kernel(const float* __restrict__ x, float* __restrict__ xp) {
    const int total = B_ * C_ * N_;
    for (int idx = blockIdx.x * blockDim.x + threadIdx.x; idx < total;
         idx += gridDim.x * blockDim.x) {
        int n = idx % N_;
        int bc = idx / N_;
        int ow = n % WP, oh = n / WP;
        const float* px = x + ((size_t)bc * H_ + 2 * oh) * W_ + 2 * ow;
        float2 a = *reinterpret_cast<const float2*>(px);
        float2 b = *reinterpret_cast<const float2*>(px + W_);
        xp[idx] = fmaxf(fmaxf(a.x, a.y), fmaxf(b.x, b.y));
    }
}

// ------------------------------------------------- weight fusion: Wf = Wr@Ww
__global__ __launch_bounds__(256) void fuse_w_kernel(const float* __restrict__ Wr,
                                                     const float* __restrict__ Ww,
                                                     float* __restrict__ Wf) {
    int o = blockIdx.x;    // 0..511
    int v = threadIdx.x;   // 0..255
    float s = 0.f;
    for (int c = 0; c < OD; ++c)
        s = fmaf(Wr[(size_t)o * OD + c], Ww[(size_t)c * VD + v], s);
    Wf[(size_t)o * VD + v] = s;
}

__global__ void fuse_bias_kernel(const float* __restrict__ Wr,
                                 const float* __restrict__ bw,
                                 float* __restrict__ bf) {
    int o = blockIdx.x * blockDim.x + threadIdx.x;
    if (o < OD) {
        float s = 0.f;
        for (int c = 0; c < OD; ++c) s = fmaf(Wr[(size_t)o * OD + c], bw[c], s);
        bf[o] = s;
    }
}

// ---------------------------------------------- qk + value GEMMs (per batch)
// M=512 (rows 0..255 -> qk with BN+ReLU, 256..511 -> value with bias), K=512
__global__ __launch_bounds__(256) void qkv_gemm(
    const float* __restrict__ Wk, const float* __restrict__ Wv,
    const float* __restrict__ xp,
    const float* __restrict__ kg, const float* __restrict__ kb,
    const float* __restrict__ km, const float* __restrict__ kv,
    const float* __restrict__ bv,
    float* __restrict__ qk, float* __restrict__ value) {
    const int b = blockIdx.z;
    const int row0 = blockIdx.y * 64;   // 0..448
    const int col0 = blockIdx.x * 64;
    const bool is_q = (row0 < 256);
    const float* Wsrc = is_q ? (Wk + (size_t)row0 * 512)
                             : (Wv + (size_t)(row0 - 256) * 512);
    const float* Xb = xp + (size_t)b * 512 * N_;

    __shared__ __align__(16) float As[16][64];       // [k][m]
    __shared__ __align__(16) float Xs[16][68];       // [k][n], padded

    float acc[4][4] = {};
    const int tid = threadIdx.x;
    const int tx = tid & 15, ty = tid >> 4;
    const int tm0 = ty * 4, tn0 = tx * 4;

    for (int k0 = 0; k0 < 512; k0 += 16) {
#pragma unroll
        for (int i = 0; i < 4; ++i) {
            int idx = tid + i * 256;            // 0..1023
            int m = idx >> 4, kk = idx & 15;
            As[kk][m] = Wsrc[(size_t)m * 512 + k0 + kk];
        }
#pragma unroll
        for (int i = 0; i < 4; ++i) {
            int idx = tid + i * 256;
            int kk = idx >> 6, n = idx & 63;
            Xs[kk][n] = Xb[(size_t)(k0 + kk) * N_ + col0 + n];
        }
        __syncthreads();
#pragma unroll
        for (int kk = 0; kk < 16; ++kk) {
            float4 a4 = *reinterpret_cast<const float4*>(&As[kk][tm0]);
            float4 x4 = *reinterpret_cast<const float4*>(&Xs[kk][tn0]);
            float a[4] = {a4.x, a4.y, a4.z, a4.w};
            float xv[4] = {x4.x, x4.y, x4.z, x4.w};
#pragma unroll
            for (int i = 0; i < 4; ++i)
#pragma unroll
                for (int j = 0; j < 4; ++j)
                    acc[i][j] = fmaf(a[i], xv[j], acc[i][j]);
        }
        __syncthreads();
    }

    if (is_q) {
#pragma unroll
        for (int i = 0; i < 4; ++i) {
            int o = row0 + tm0 + i;
            float inv = kg[o] * rsqrtf(kv[o] + EPSV);
            float add = kb[o] - km[o] * inv;
            float* dst = qk + ((size_t)b * KD + o) * N_ + col0 + tn0;
#pragma unroll
            for (int j = 0; j < 4; ++j)
                dst[j] = fmaxf(acc[i][j] * inv + add, 0.f);
        }
    } else {
#pragma unroll
        for (int i = 0; i < 4; ++i) {
            int o = row0 + tm0 + i - 256;
            float bb = bv[o];
            float* dst = value + ((size_t)b * VD + o) * N_ + col0 + tn0;
#pragma unroll
            for (int j = 0; j < 4; ++j)
                dst[j] = acc[i][j] + bb;
        }
    }
}

// ------------------------------------------------------ flash-style attention
// block: 256 threads, one (batch, 32-query tile). Streams 32-wide m tiles.
__global__ __launch_bounds__(256) void attn_kernel(const float* __restrict__ qk,
                                                   const float* __restrict__ value,
                                                   float* __restrict__ ctx) {
    const int b = blockIdx.y;
    const int n0 = blockIdx.x * 32;
    const int tid = threadIdx.x;

    __shared__ __align__(16) float Qs[256][32];   // [k][n]
    __shared__ __align__(16) float Kc[32][36];    // k-chunk [k][m]
    __shared__ __align__(16) float Vc[64][36];    // v-chunk [v][m]
    __shared__ __align__(16) float Ps[32][36];    // P[n][m]
    __shared__ float m_s[32], l_s[32], corr_s[32];

    const float scale = 0.0625f;   // 256^-0.5

    const float* Qb = qk + (size_t)b * KD * N_;
    const float* Vb = value + (size_t)b * VD * N_;

    for (int i = tid; i < 256 * 32; i += 256) {
        int n = i & 31, k = i >> 5;
        Qs[k][n] = Qb[(size_t)k * N_ + n0 + n];
    }
    if (tid < 32) { m_s[tid] = -1e30f; l_s[tid] = 0.f; }

    const int an = tid & 31;         // O column (query) this thread owns
    const int vg = tid >> 5;         // v group 0..7
    const int sn = tid >> 3;         // S row 0..31
    const int sm0 = (tid & 7) * 4;   // S col base
    float O[4][8] = {};              // [v-chunk][r]; v = chunk*64 + vg*8 + r

    __syncthreads();

    for (int m0 = 0; m0 < N_; m0 += 32) {
        // ---- S = Q^T K (tile), accumulate over k chunks of 32
        float S[4] = {0.f, 0.f, 0.f, 0.f};
        for (int kc = 0; kc < 256; kc += 32) {
            for (int i = tid; i < 32 * 32; i += 256) {
                int m = i & 31, k = i >> 5;
                Kc[k][m] = Qb[(size_t)(kc + k) * N_ + m0 + m];
            }
            __syncthreads();
#pragma unroll
            for (int k = 0; k < 32; ++k) {
                float q = Qs[kc + k][sn];
                float4 k4 = *reinterpret_cast<const float4*>(&Kc[k][sm0]);
                S[0] = fmaf(q, k4.x, S[0]);
                S[1] = fmaf(q, k4.y, S[1]);
                S[2] = fmaf(q, k4.z, S[2]);
                S[3] = fmaf(q, k4.w, S[3]);
            }
            __syncthreads();
        }
#pragma unroll
        for (int j = 0; j < 4; ++j) S[j] *= scale;

        // ---- online softmax stats (8 threads per row sn)
        float mx = fmaxf(fmaxf(S[0], S[1]), fmaxf(S[2], S[3]));
#pragma unroll
        for (int off = 4; off >= 1; off >>= 1) mx = fmaxf(mx, __shfl_xor(mx, off, 8));
        float mold = m_s[sn];                 // lockstep read-before-masked-write in wave
        float mnew = fmaxf(mold, mx);
        float p[4]; float psum = 0.f;
#pragma unroll
        for (int j = 0; j < 4; ++j) { p[j] = __expf(S[j] - mnew); psum += p[j]; }
#pragma unroll
        for (int off = 4; off >= 1; off >>= 1) psum += __shfl_xor(psum, off, 8);
        if ((tid & 7) == 0) {
            float corr = __expf(mold - mnew);
            corr_s[sn] = corr;
            m_s[sn] = mnew;
            l_s[sn] = l_s[sn] * corr + psum;
        }
#pragma unroll
        for (int j = 0; j < 4; ++j) Ps[sn][sm0 + j] = p[j];
        __syncthreads();

        // ---- rescale O, then accumulate P·V over 4 v-chunks of 64
        float corr = corr_s[an];
#pragma unroll
        for (int c = 0; c < 4; ++c)
#pragma unroll
            for (int r = 0; r < 8; ++r) O[c][r] *= corr;

#pragma unroll
        for (int c = 0; c < 4; ++c) {
            for (int i = tid; i < 64 * 32; i += 256) {
                int m = i & 31, v = i >> 5;
                Vc[v][m] = Vb[(size_t)(c * 64 + v) * N_ + m0 + m];
            }
            __syncthreads();
#pragma unroll
            for (int m4 = 0; m4 < 8; ++m4) {
                float4 p4 = *reinterpret_cast<const float4*>(&Ps[an][m4 * 4]);
#pragma unroll
                for (int r = 0; r < 8; ++r) {
                    float4 v4 = *reinterpret_cast<const float4*>(&Vc[vg * 8 + r][m4 * 4]);
                    O[c][r] = fmaf(p4.x, v4.x, O[c][r]);
                    O[c][r] = fmaf(p4.y, v4.y, O[c][r]);
                    O[c][r] = fmaf(p4.z, v4.z, O[c][r]);
                    O[c][r] = fmaf(p4.w, v4.w, O[c][r]);
                }
            }
            __syncthreads();
        }
    }

    float inv_l = 1.0f / l_s[an];
    float* Cb = ctx + (size_t)b * VD * N_;
#pragma unroll
    for (int c = 0; c < 4; ++c)
#pragma unroll
        for (int r = 0; r < 8; ++r) {
            int v = c * 64 + vg * 8 + r;
            Cb[(size_t)v * N_ + n0 + an] = O[c][r] * inv_l;
        }
}

// ------------------------------------------ fused out conv: Z = Wf@ctx + bf
__global__ __launch_bounds__(256) void out_gemm(const float* __restrict__ Wf,
                                                const float* __restrict__ bf,
                                                const float* __restrict__ ctx,
                                                float* __restrict__ Z) {
    const int b = blockIdx.z;
    const int row0 = blockIdx.y * 64;
    const int col0 = blockIdx.x * 64;
    const float* Xb = ctx + (size_t)b * VD * N_;

    __shared__ __align__(16) float As[16][64];
    __shared__ __align__(16) float Xs[16][68];

    float acc[4][4] = {};
    const int tid = threadIdx.x;
    const int tx = tid & 15, ty = tid >> 4;
    const int tm0 = ty * 4, tn0 = tx * 4;

    for (int k0 = 0; k0 < VD; k0 += 16) {
#pragma unroll
        for (int i = 0; i < 4; ++i) {
            int idx = tid + i * 256;
            int m = idx >> 4, kk = idx & 15;
            As[kk][m] = Wf[(size_t)(row0 + m) * VD + k0 + kk];
        }
#pragma unroll
        for (int i = 0; i < 4; ++i) {
            int idx = tid + i * 256;
            int kk = idx >> 6, n = idx & 63;
            Xs[kk][n] = Xb[(size_t)(k0 + kk) * N_ + col0 + n];
        }
        __syncthreads();
#pragma unroll
        for (int kk = 0; kk < 16; ++kk) {
            float4 a4 = *reinterpret_cast<const float4*>(&As[kk][tm0]);
            float4 x4 = *reinterpret_cast<const float4*>(&Xs[kk][tn0]);
            float a[4] = {a4.x, a4.y, a4.z, a4.w};
            float xv[4] = {x4.x, x4.y, x4.z, x4.w};
#pragma unroll
            for (int i = 0; i < 4; ++i)
#pragma unroll
                for (int j = 0; j < 4; ++j)
                    acc[i][j] = fmaf(a[i], xv[j], acc[i][j]);
        }
        __syncthreads();
    }

#pragma unroll
    for (int i = 0; i < 4; ++i) {
        int o = row0 + tm0 + i;
        float bb = bf[o];
        float* dst = Z + ((size_t)b * OD + o) * N_ + col0 + tn0;
#pragma unroll
        for (int j = 0; j < 4; ++j) dst[j] = acc[i][j] + bb;
    }
}

// --------------------------- bilinear upsample (align_corners) + BN + ReLU
__global__ void upsample_kernel(const float* __restrict__ Z,
                                const float* __restrict__ rg, const float* __restrict__ rb,
                                const float* __restrict__ rm, const float* __restrict__ rv,
                                float* __restrict__ out) {
    const int total = B_ * OD * H_ * W_;
    const float s = 47.0f / 95.0f;   // (HP-1)/(H-1), align_corners=True
    for (int idx = blockIdx.x * blockDim.x + threadIdx.x; idx < total;
         idx += gridDim.x * blockDim.x) {
        int x = idx % W_;
        int t = idx / W_;
        int y = t % H_;
        int bo = t / H_;
        int o = bo % OD;
        float fy = y * s, fx = x * s;
        int y0 = (int)fy, x0 = (int)fx;
        int y1 = min(y0 + 1, HP - 1), x1 = min(x0 + 1, WP - 1);
        float wy = fy - y0, wx = fx - x0;
        const float* Zp = Z + (size_t)bo * N_;
        float v00 = Zp[y0 * WP + x0], v01 = Zp[y0 * WP + x1];
        float v10 = Zp[y1 * WP + x0], v11 = Zp[y1 * WP + x1];
        float r0 = v00 + (v01 - v00) * wx;
        float r1 = v10 + (v11 - v10) * wx;
        float v = r0 + (r1 - r0) * wy;
        float inv = rg[o] * rsqrtf(rv[o] + EPSV);
        float add = rb[o] - rm[o] * inv;
        out[idx] = fmaxf(v * inv + add, 0.f);
    }
}

extern "C" void kernel_launch(void* const* d_in, const int* in_sizes, int n_in,
                              void* d_out, int out_size, void* d_ws, size_t ws_size,
                              hipStream_t stream) {
    const float* x  = (const float*)d_in[0];
    const float* Wk = (const float*)d_in[1];
    const float* kg = (const float*)d_in[2];
    const float* kb = (const float*)d_in[3];
    const float* km = (const float*)d_in[4];
    const float* kvv= (const float*)d_in[5];
    const float* Wv = (const float*)d_in[6];
    const float* bv = (const float*)d_in[7];
    const float* Ww = (const float*)d_in[8];
    const float* bw = (const float*)d_in[9];
    const float* Wr = (const float*)d_in[10];
    const float* rg = (const float*)d_in[11];
    const float* rb = (const float*)d_in[12];
    const float* rm = (const float*)d_in[13];
    const float* rv = (const float*)d_in[14];

    float* ws  = (float*)d_ws;
    float* xp  = ws + OFF_XP;
    float* qk  = ws + OFF_QK;
    float* val = ws + OFF_VAL;
    float* ctx = ws + OFF_CTX;
    float* Wf  = ws + OFF_WF;
    float* bf  = ws + OFF_BF;
    float* Z   = ws + OFF_Z;   // overlays xp (dead after qkv_gemm)
    float* out = (float*)d_out;

    maxpool_kernel<<<2048, 256, 0, stream>>>(x, xp);
    fuse_w_kernel<<<OD, 256, 0, stream>>>(Wr, Ww, Wf);
    fuse_bias_kernel<<<2, 256, 0, stream>>>(Wr, bw, bf);
    qkv_gemm<<<dim3(N_ / 64, 8, B_), 256, 0, stream>>>(Wk, Wv, xp, kg, kb, km, kvv, bv, qk, val);
    attn_kernel<<<dim3(N_ / 32, B_), 256, 0, stream>>>(qk, val, ctx);
    out_gemm<<<dim3(N_ / 64, OD / 64, B_), 256, 0, stream>>>(Wf, bf, ctx, Z);
    upsample_kernel<<<4096, 256, 0, stream>>>(Z, rg, rb, rm, rv, out);
}

// Round 2
// 1072.807 us; speedup vs baseline: 13.0108x; 13.0108x over previous
//
#include <hip/hip_runtime.h>
#include <math.h>

typedef __attribute__((ext_vector_type(8))) short bf16x8;
typedef __attribute__((ext_vector_type(4))) float f32x4;

namespace {

constexpr int B_ = 8, C_ = 512, H_ = 96, W_ = 96;
constexpr int HP = 48, WP = 48, N_ = HP * WP;   // pooled spatial, N=2304
constexpr int KD = 256, VD = 256, OD = 512;
constexpr float EPSV = 1e-5f;

// workspace byte offsets
constexpr size_t BOFF_XP  = 0;                                      // fp32 [B][C][N]; Z overlays later
constexpr size_t BOFF_QKT = BOFF_XP  + (size_t)B_ * C_ * N_ * 4;    // bf16 [B][N][KD]
constexpr size_t BOFF_VAL = BOFF_QKT + (size_t)B_ * N_ * KD * 2;    // bf16 [B][VD][N]
constexpr size_t BOFF_CTX = BOFF_VAL + (size_t)B_ * VD * N_ * 2;    // fp32 [B][VD][N]
constexpr size_t BOFF_WF  = BOFF_CTX + (size_t)B_ * VD * N_ * 4;    // fp32 [OD][VD]
constexpr size_t BOFF_BF  = BOFF_WF  + (size_t)OD * VD * 4;         // fp32 [OD]

} // namespace

__device__ __forceinline__ ushort f2bf(float f) {
    union { float f; unsigned u; } x; x.f = f;
    unsigned r = x.u + 0x7FFFu + ((x.u >> 16) & 1u);
    return (ushort)(r >> 16);
}

// ---------------------------------------------------------------- maxpool 2x2
__global__ void maxpool_kernel(const float* __restrict__ x, float* __restrict__ xp) {
    const int total = B_ * C_ * N_;
    for (int idx = blockIdx.x * blockDim.x + threadIdx.x; idx < total;
         idx += gridDim.x * blockDim.x) {
        int n = idx % N_;
        int bc = idx / N_;
        int ow = n % WP, oh = n / WP;
        const float* px = x + ((size_t)bc * H_ + 2 * oh) * W_ + 2 * ow;
        float2 a = *reinterpret_cast<const float2*>(px);
        float2 b = *reinterpret_cast<const float2*>(px + W_);
        xp[idx] = fmaxf(fmaxf(a.x, a.y), fmaxf(b.x, b.y));
    }
}

// ------------------------------------------------- weight fusion: Wf = Wr@Ww
__global__ __launch_bounds__(256) void fuse_w_kernel(const float* __restrict__ Wr,
                                                     const float* __restrict__ Ww,
                                                     float* __restrict__ Wf) {
    int o = blockIdx.x;    // 0..511
    int v = threadIdx.x;   // 0..255
    float s = 0.f;
    for (int c = 0; c < OD; ++c)
        s = fmaf(Wr[(size_t)o * OD + c], Ww[(size_t)c * VD + v], s);
    Wf[(size_t)o * VD + v] = s;
}

__global__ void fuse_bias_kernel(const float* __restrict__ Wr,
                                 const float* __restrict__ bw,
                                 float* __restrict__ bf) {
    int o = blockIdx.x * blockDim.x + threadIdx.x;
    if (o < OD) {
        float s = 0.f;
        for (int c = 0; c < OD; ++c) s = fmaf(Wr[(size_t)o * OD + c], bw[c], s);
        bf[o] = s;
    }
}

// ---------------------------------------------- qk + value GEMMs (per batch)
// M=512 (rows 0..255 -> qkT bf16 [n][k] with BN+ReLU, 256..511 -> value bf16)
__global__ __launch_bounds__(256) void qkv_gemm(
    const float* __restrict__ Wk, const float* __restrict__ Wv,
    const float* __restrict__ xp,
    const float* __restrict__ kg, const float* __restrict__ kb,
    const float* __restrict__ km, const float* __restrict__ kv,
    const float* __restrict__ bv,
    ushort* __restrict__ qkT, ushort* __restrict__ value) {
    const int b = blockIdx.z;
    const int row0 = blockIdx.y * 64;   // 0..448
    const int col0 = blockIdx.x * 64;
    const bool is_q = (row0 < 256);
    const float* Wsrc = is_q ? (Wk + (size_t)row0 * 512)
                             : (Wv + (size_t)(row0 - 256) * 512);
    const float* Xb = xp + (size_t)b * 512 * N_;

    __shared__ __align__(16) float As[16][64];       // [k][m]
    __shared__ __align__(16) float Xs[16][68];       // [k][n], padded

    float acc[4][4] = {};
    const int tid = threadIdx.x;
    const int tx = tid & 15, ty = tid >> 4;
    const int tm0 = ty * 4, tn0 = tx * 4;

    for (int k0 = 0; k0 < 512; k0 += 16) {
#pragma unroll
        for (int i = 0; i < 4; ++i) {
            int idx = tid + i * 256;            // 0..1023
            int m = idx >> 4, kk = idx & 15;
            As[kk][m] = Wsrc[(size_t)m * 512 + k0 + kk];
        }
#pragma unroll
        for (int i = 0; i < 4; ++i) {
            int idx = tid + i * 256;
            int kk = idx >> 6, n = idx & 63;
            Xs[kk][n] = Xb[(size_t)(k0 + kk) * N_ + col0 + n];
        }
        __syncthreads();
#pragma unroll
        for (int kk = 0; kk < 16; ++kk) {
            float4 a4 = *reinterpret_cast<const float4*>(&As[kk][tm0]);
            float4 x4 = *reinterpret_cast<const float4*>(&Xs[kk][tn0]);
            float a[4] = {a4.x, a4.y, a4.z, a4.w};
            float xv[4] = {x4.x, x4.y, x4.z, x4.w};
#pragma unroll
            for (int i = 0; i < 4; ++i)
#pragma unroll
                for (int j = 0; j < 4; ++j)
                    acc[i][j] = fmaf(a[i], xv[j], acc[i][j]);
        }
        __syncthreads();
    }

    if (is_q) {
#pragma unroll
        for (int i = 0; i < 4; ++i) {
            int o = row0 + tm0 + i;            // k-channel
            float inv = kg[o] * rsqrtf(kv[o] + EPSV);
            float add = kb[o] - km[o] * inv;
#pragma unroll
            for (int j = 0; j < 4; ++j) {
                float q = fmaxf(acc[i][j] * inv + add, 0.f);
                // transposed store: qkT[b][n][k]
                qkT[((size_t)b * N_ + col0 + tn0 + j) * KD + o] = f2bf(q);
            }
        }
    } else {
#pragma unroll
        for (int i = 0; i < 4; ++i) {
            int o = row0 + tm0 + i - 256;
            float bb = bv[o];
            ushort4 pk;
            pk.x = f2bf(acc[i][0] + bb);
            pk.y = f2bf(acc[i][1] + bb);
            pk.z = f2bf(acc[i][2] + bb);
            pk.w = f2bf(acc[i][3] + bb);
            *reinterpret_cast<ushort4*>(&value[((size_t)b * VD + o) * N_ + col0 + tn0]) = pk;
        }
    }
}

// ------------------------------------------------------ MFMA flash attention
// 4 independent waves per block; wave owns 16 query rows, full V in acc regs.
// No __syncthreads anywhere: P transpose goes through per-wave swizzled LDS.
__global__ __launch_bounds__(256) void attn_mfma(const ushort* __restrict__ qkT,
                                                 const ushort* __restrict__ val,
                                                 float* __restrict__ ctx) {
    __shared__ ushort Plds[4][1024];   // per-wave [16 n][64 m] bf16, XOR-swizzled

    const int b = blockIdx.y;
    const int n0 = blockIdx.x * 64;
    const int w  = threadIdx.x >> 6;
    const int l  = threadIdx.x & 63;
    const int lr = l & 15, lg = l >> 4;

    const ushort* Qb = qkT + (size_t)b * N_ * KD;
    const ushort* Vb = val + (size_t)b * VD * N_;

    // resident Q fragments: rows n0 + w*16 .. +15, all K=256 (8 chunks of 32)
    bf16x8 qf[8];
    {
        const ushort* qrow = Qb + (size_t)(n0 + w * 16 + lr) * KD + lg * 8;
#pragma unroll
        for (int kc = 0; kc < 8; ++kc)
            qf[kc] = *reinterpret_cast<const bf16x8*>(qrow + kc * 32);
    }

    f32x4 O[16];
#pragma unroll
    for (int vt = 0; vt < 16; ++vt) O[vt] = (f32x4){0.f, 0.f, 0.f, 0.f};
    float mrun[4] = {-1e30f, -1e30f, -1e30f, -1e30f};
    float lrun[4] = {0.f, 0.f, 0.f, 0.f};

    ushort* Pw = &Plds[w][0];

    for (int it = 0; it < N_ / 64; ++it) {
        const int m0 = it * 64;

        // ---- S[16n x 64m] = Q^T K  (K frags straight from L2-resident qkT)
        f32x4 S[4];
#pragma unroll
        for (int mt = 0; mt < 4; ++mt) S[mt] = (f32x4){0.f, 0.f, 0.f, 0.f};
        const ushort* kbase = Qb + (size_t)(m0 + lr) * KD + lg * 8;
#pragma unroll
        for (int kc = 0; kc < 8; ++kc) {
#pragma unroll
            for (int mt = 0; mt < 4; ++mt) {
                bf16x8 kf = *reinterpret_cast<const bf16x8*>(kbase + (size_t)mt * 16 * KD + kc * 32);
                S[mt] = __builtin_amdgcn_mfma_f32_16x16x32_bf16(qf[kc], kf, S[mt], 0, 0, 0);
            }
        }
#pragma unroll
        for (int mt = 0; mt < 4; ++mt) S[mt] *= 0.0625f;   // 256^-0.5

        // ---- online softmax (rows n = lg*4 + r; m spread over 16 lanes x 4 mt)
        float corr[4];
#pragma unroll
        for (int r = 0; r < 4; ++r) {
            float mx = fmaxf(fmaxf(S[0][r], S[1][r]), fmaxf(S[2][r], S[3][r]));
#pragma unroll
            for (int off = 1; off < 16; off <<= 1) mx = fmaxf(mx, __shfl_xor(mx, off, 16));
            const float mn = fmaxf(mrun[r], mx);
            const float c  = __expf(mrun[r] - mn);
            corr[r] = c; mrun[r] = mn;
            const int row = lg * 4 + r;
            float ps = 0.f;
#pragma unroll
            for (int mt = 0; mt < 4; ++mt) {
                float p = __expf(S[mt][r] - mn);
                ps += p;
                Pw[(row * 64 + mt * 16 + lr) ^ ((row & 7) << 3)] = f2bf(p);
            }
#pragma unroll
            for (int off = 1; off < 16; off <<= 1) ps += __shfl_xor(ps, off, 16);
            lrun[r] = lrun[r] * c + ps;
        }

        // ---- rescale O
#pragma unroll
        for (int vt = 0; vt < 16; ++vt) {
            f32x4 o = O[vt];
            o[0] *= corr[0]; o[1] *= corr[1]; o[2] *= corr[2]; o[3] *= corr[3];
            O[vt] = o;
        }

        // ---- P fragments back from LDS (transpose: A rows = n = lr)
        bf16x8 pf0 = *reinterpret_cast<const bf16x8*>(&Pw[(lr * 64 +  0 + lg * 8) ^ ((lr & 7) << 3)]);
        bf16x8 pf1 = *reinterpret_cast<const bf16x8*>(&Pw[(lr * 64 + 32 + lg * 8) ^ ((lr & 7) << 3)]);

        // ---- O[16n x 256v] += P · V^T  (V frags from L2-resident val)
        const ushort* vbase = Vb + (size_t)lr * N_ + m0 + lg * 8;
#pragma unroll
        for (int vt = 0; vt < 16; ++vt) {
            const ushort* vrow = vbase + (size_t)vt * 16 * N_;
            bf16x8 vf0 = *reinterpret_cast<const bf16x8*>(vrow);
            bf16x8 vf1 = *reinterpret_cast<const bf16x8*>(vrow + 32);
            O[vt] = __builtin_amdgcn_mfma_f32_16x16x32_bf16(pf0, vf0, O[vt], 0, 0, 0);
            O[vt] = __builtin_amdgcn_mfma_f32_16x16x32_bf16(pf1, vf1, O[vt], 0, 0, 0);
        }
    }

    // ---- epilogue: divide by softmax denom, store ctx fp32 [b][v][n]
    float il[4];
#pragma unroll
    for (int r = 0; r < 4; ++r) il[r] = 1.f / lrun[r];
    float* Cb = ctx + (size_t)b * VD * N_ + n0 + w * 16 + lg * 4;
#pragma unroll
    for (int vt = 0; vt < 16; ++vt) {
        float4 st;
        st.x = O[vt][0] * il[0];
        st.y = O[vt][1] * il[1];
        st.z = O[vt][2] * il[2];
        st.w = O[vt][3] * il[3];
        *reinterpret_cast<float4*>(Cb + (size_t)(vt * 16 + lr) * N_) = st;
    }
}

// ------------------------------------------ fused out conv: Z = Wf@ctx + bf
__global__ __launch_bounds__(256) void out_gemm(const float* __restrict__ Wf,
                                                const float* __restrict__ bf,
                                                const float* __restrict__ ctx,
                                                float* __restrict__ Z) {
    const int b = blockIdx.z;
    const int row0 = blockIdx.y * 64;
    const int col0 = blockIdx.x * 64;
    const float* Xb = ctx + (size_t)b * VD * N_;

    __shared__ __align__(16) float As[16][64];
    __shared__ __align__(16) float Xs[16][68];

    float acc[4][4] = {};
    const int tid = threadIdx.x;
    const int tx = tid & 15, ty = tid >> 4;
    const int tm0 = ty * 4, tn0 = tx * 4;

    for (int k0 = 0; k0 < VD; k0 += 16) {
#pragma unroll
        for (int i = 0; i < 4; ++i) {
            int idx = tid + i * 256;
            int m = idx >> 4, kk = idx & 15;
            As[kk][m] = Wf[(size_t)(row0 + m) * VD + k0 + kk];
        }
#pragma unroll
        for (int i = 0; i < 4; ++i) {
            int idx = tid + i * 256;
            int kk = idx >> 6, n = idx & 63;
            Xs[kk][n] = Xb[(size_t)(k0 + kk) * N_ + col0 + n];
        }
        __syncthreads();
#pragma unroll
        for (int kk = 0; kk < 16; ++kk) {
            float4 a4 = *reinterpret_cast<const float4*>(&As[kk][tm0]);
            float4 x4 = *reinterpret_cast<const float4*>(&Xs[kk][tn0]);
            float a[4] = {a4.x, a4.y, a4.z, a4.w};
            float xv[4] = {x4.x, x4.y, x4.z, x4.w};
#pragma unroll
            for (int i = 0; i < 4; ++i)
#pragma unroll
                for (int j = 0; j < 4; ++j)
                    acc[i][j] = fmaf(a[i], xv[j], acc[i][j]);
        }
        __syncthreads();
    }

#pragma unroll
    for (int i = 0; i < 4; ++i) {
        int o = row0 + tm0 + i;
        float bb = bf[o];
        float* dst = Z + ((size_t)b * OD + o) * N_ + col0 + tn0;
#pragma unroll
        for (int j = 0; j < 4; ++j) dst[j] = acc[i][j] + bb;
    }
}

// --------------------------- bilinear upsample (align_corners) + BN + ReLU
__global__ void upsample_kernel(const float* __restrict__ Z,
                                const float* __restrict__ rg, const float* __restrict__ rb,
                                const float* __restrict__ rm, const float* __restrict__ rv,
                                float* __restrict__ out) {
    const int total = B_ * OD * H_ * W_;
    const float s = 47.0f / 95.0f;   // (HP-1)/(H-1), align_corners=True
    for (int idx = blockIdx.x * blockDim.x + threadIdx.x; idx < total;
         idx += gridDim.x * blockDim.x) {
        int x = idx % W_;
        int t = idx / W_;
        int y = t % H_;
        int bo = t / H_;
        int o = bo % OD;
        float fy = y * s, fx = x * s;
        int y0 = (int)fy, x0 = (int)fx;
        int y1 = min(y0 + 1, HP - 1), x1 = min(x0 + 1, WP - 1);
        float wy = fy - y0, wx = fx - x0;
        const float* Zp = Z + (size_t)bo * N_;
        float v00 = Zp[y0 * WP + x0], v01 = Zp[y0 * WP + x1];
        float v10 = Zp[y1 * WP + x0], v11 = Zp[y1 * WP + x1];
        float r0 = v00 + (v01 - v00) * wx;
        float r1 = v10 + (v11 - v10) * wx;
        float v = r0 + (r1 - r0) * wy;
        float inv = rg[o] * rsqrtf(rv[o] + EPSV);
        float add = rb[o] - rm[o] * inv;
        out[idx] = fmaxf(v * inv + add, 0.f);
    }
}

extern "C" void kernel_launch(void* const* d_in, const int* in_sizes, int n_in,
                              void* d_out, int out_size, void* d_ws, size_t ws_size,
                              hipStream_t stream) {
    const float* x  = (const float*)d_in[0];
    const float* Wk = (const float*)d_in[1];
    const float* kg = (const float*)d_in[2];
    const float* kb = (const float*)d_in[3];
    const float* km = (const float*)d_in[4];
    const float* kvv= (const float*)d_in[5];
    const float* Wv = (const float*)d_in[6];
    const float* bv = (const float*)d_in[7];
    const float* Ww = (const float*)d_in[8];
    const float* bw = (const float*)d_in[9];
    const float* Wr = (const float*)d_in[10];
    const float* rg = (const float*)d_in[11];
    const float* rb = (const float*)d_in[12];
    const float* rm = (const float*)d_in[13];
    const float* rv = (const float*)d_in[14];

    char* wsb = (char*)d_ws;
    float*  xp   = (float*)(wsb + BOFF_XP);
    ushort* qkT  = (ushort*)(wsb + BOFF_QKT);
    ushort* valp = (ushort*)(wsb + BOFF_VAL);
    float*  ctx  = (float*)(wsb + BOFF_CTX);
    float*  Wf   = (float*)(wsb + BOFF_WF);
    float*  bf   = (float*)(wsb + BOFF_BF);
    float*  Z    = xp;   // xp dead after qkv_gemm
    float*  out  = (float*)d_out;

    maxpool_kernel<<<2048, 256, 0, stream>>>(x, xp);
    fuse_w_kernel<<<OD, 256, 0, stream>>>(Wr, Ww, Wf);
    fuse_bias_kernel<<<2, 256, 0, stream>>>(Wr, bw, bf);
    qkv_gemm<<<dim3(N_ / 64, 8, B_), 256, 0, stream>>>(Wk, Wv, xp, kg, kb, km, kvv, bv, qkT, valp);
    attn_mfma<<<dim3(N_ / 64, B_), 256, 0, stream>>>(qkT, valp, ctx);
    out_gemm<<<dim3(N_ / 64, OD / 64, B_), 256, 0, stream>>>(Wf, bf, ctx, Z);
    upsample_kernel<<<4096, 256, 0, stream>>>(Z, rg, rb, rm, rv, out);
}

// Round 3
// 843.444 us; speedup vs baseline: 16.5490x; 1.2719x over previous
//
#include <hip/hip_runtime.h>
#include <math.h>

typedef __attribute__((ext_vector_type(8))) short bf16x8;
typedef __attribute__((ext_vector_type(4))) float f32x4;

namespace {

constexpr int B_ = 8, C_ = 512, H_ = 96, W_ = 96;
constexpr int HP = 48, WP = 48, N_ = HP * WP;   // pooled spatial, N=2304
constexpr int KD = 256, VD = 256, OD = 512;
constexpr float EPSV = 1e-5f;

// workspace byte offsets
constexpr size_t BOFF_XPT = 0;                                       // bf16 [B][N][C]
constexpr size_t BOFF_QKT = BOFF_XPT + (size_t)B_ * N_ * C_ * 2;     // bf16 [B][N][KD]
constexpr size_t BOFF_VAL = BOFF_QKT + (size_t)B_ * N_ * KD * 2;     // bf16 [B][VD][N]
constexpr size_t BOFF_CTX = BOFF_VAL + (size_t)B_ * VD * N_ * 2;     // fp32 [B][VD][N]
constexpr size_t BOFF_W2  = BOFF_CTX + (size_t)B_ * VD * N_ * 4;     // bf16 [512][512]
constexpr size_t BOFF_WF  = BOFF_W2  + (size_t)512 * 512 * 2;        // fp32 [OD][VD]
constexpr size_t BOFF_BF  = BOFF_WF  + (size_t)OD * VD * 4;          // fp32 [OD]
// Z fp32 [B][OD][N] (37.7MB) overlays [xpT+qkT+val] (exactly 37.7MB), all dead by then

} // namespace

__device__ __forceinline__ ushort f2bf(float f) {
    union { float f; unsigned u; } x; x.f = f;
    unsigned r = x.u + 0x7FFFu + ((x.u >> 16) & 1u);
    return (ushort)(r >> 16);
}

// ------------------------ fused maxpool 2x2 + transpose + bf16: x -> xpT[b][n][c]
// block: (b, oh, ctile64); 192 threads; LDS transpose
__global__ __launch_bounds__(192) void pool_t_kernel(const float* __restrict__ x,
                                                     ushort* __restrict__ xpT) {
    __shared__ float ps[64][49];
    const int gid = blockIdx.x;
    const int ct = gid & 7;          // c-tile (64 channels)
    const int tmp = gid >> 3;
    const int oh = tmp % 48;
    const int b  = tmp / 48;
    const int t = threadIdx.x;
    const int ow = t % 48, ci = t / 48;   // ci 0..3

    const int c0 = ct * 64;
#pragma unroll
    for (int pass = 0; pass < 16; ++pass) {
        const int c = pass * 4 + ci;
        const float* px = x + (((size_t)b * C_ + c0 + c) * H_ + 2 * oh) * W_ + 2 * ow;
        float2 a = *reinterpret_cast<const float2*>(px);
        float2 d = *reinterpret_cast<const float2*>(px + W_);
        ps[c][ow] = fmaxf(fmaxf(a.x, a.y), fmaxf(d.x, d.y));
    }
    __syncthreads();
    const int cc = t & 63;
    const int nr0 = t >> 6;          // 0..2
#pragma unroll
    for (int pass = 0; pass < 16; ++pass) {
        const int nr = pass * 3 + nr0;     // 0..47
        xpT[((size_t)b * N_ + oh * 48 + nr) * C_ + c0 + cc] = f2bf(ps[cc][nr]);
    }
}

// ------------------------------------ pack Wk|Wv into bf16 W2 [512][512]
__global__ __launch_bounds__(256) void w2_kernel(const float* __restrict__ Wk,
                                                 const float* __restrict__ Wv,
                                                 ushort* __restrict__ W2) {
    const int m = blockIdx.x;        // 0..511
    const float* src = (m < 256) ? (Wk + (size_t)m * 512) : (Wv + (size_t)(m - 256) * 512);
    const int k = threadIdx.x * 2;
    float2 v = *reinterpret_cast<const float2*>(src + k);
    ushort2 p; p.x = f2bf(v.x); p.y = f2bf(v.y);
    *reinterpret_cast<ushort2*>(&W2[(size_t)m * 512 + k]) = p;
}

// ------------------------------------------------- weight fusion: Wf = Wr@Ww
__global__ __launch_bounds__(256) void fuse_w_kernel(const float* __restrict__ Wr,
                                                     const float* __restrict__ Ww,
                                                     float* __restrict__ Wf) {
    int o = blockIdx.x;    // 0..511
    int v = threadIdx.x;   // 0..255
    float s = 0.f;
    for (int c = 0; c < OD; ++c)
        s = fmaf(Wr[(size_t)o * OD + c], Ww[(size_t)c * VD + v], s);
    Wf[(size_t)o * VD + v] = s;
}

__global__ void fuse_bias_kernel(const float* __restrict__ Wr,
                                 const float* __restrict__ bw,
                                 float* __restrict__ bf) {
    int o = blockIdx.x * blockDim.x + threadIdx.x;
    if (o < OD) {
        float s = 0.f;
        for (int c = 0; c < OD; ++c) s = fmaf(Wr[(size_t)o * OD + c], bw[c], s);
        bf[o] = s;
    }
}

// ------------------------------------- qkv MFMA GEMM: [Wk|Wv] @ xpT^T
// grid 2304 (1D): b = id&7 (XCD-pinned), my = m-tile(64), nx = n-tile(64)
__global__ __launch_bounds__(256) void qkv_mfma(
    const ushort* __restrict__ W2, const ushort* __restrict__ xpT,
    const float* __restrict__ kg, const float* __restrict__ kb,
    const float* __restrict__ km, const float* __restrict__ kv,
    const float* __restrict__ bv,
    ushort* __restrict__ qkT, ushort* __restrict__ val) {
    const int id = blockIdx.x;
    const int b = id & 7;
    const int t = id >> 3;           // 0..287
    const int my = t & 7;            // m-tile
    const int nx = t >> 3;           // 0..35
    const int w = threadIdx.x >> 6, l = threadIdx.x & 63;
    const int lr = l & 15, lg = l >> 4;

    const ushort* Xb = xpT + (size_t)b * N_ * C_;
    const int m0 = my * 64 + w * 16;
    const ushort* Arow = W2 + (size_t)(m0 + lr) * 512 + lg * 8;
    const ushort* Brow = Xb + (size_t)(nx * 64 + lr) * 512 + lg * 8;

    f32x4 acc[4];
#pragma unroll
    for (int nt = 0; nt < 4; ++nt) acc[nt] = (f32x4){0.f, 0.f, 0.f, 0.f};

#pragma unroll
    for (int kc = 0; kc < 16; ++kc) {
        bf16x8 af = *reinterpret_cast<const bf16x8*>(Arow + kc * 32);
#pragma unroll
        for (int nt = 0; nt < 4; ++nt) {
            bf16x8 bfr = *reinterpret_cast<const bf16x8*>(Brow + (size_t)nt * 16 * 512 + kc * 32);
            acc[nt] = __builtin_amdgcn_mfma_f32_16x16x32_bf16(af, bfr, acc[nt], 0, 0, 0);
        }
    }

    // C mapping: col(lane&15)=n, row=(lane>>4)*4+j = m
    if (m0 < 256) {
        // q rows -> BN+ReLU -> qkT[b][n][kd], ushort4 per (nt)
        float inv[4], add[4];
#pragma unroll
        for (int j = 0; j < 4; ++j) {
            int o = m0 + lg * 4 + j;
            inv[j] = kg[o] * rsqrtf(kv[o] + EPSV);
            add[j] = kb[o] - km[o] * inv[j];
        }
#pragma unroll
        for (int nt = 0; nt < 4; ++nt) {
            int n = nx * 64 + nt * 16 + lr;
            ushort4 q4;
            q4.x = f2bf(fmaxf(acc[nt][0] * inv[0] + add[0], 0.f));
            q4.y = f2bf(fmaxf(acc[nt][1] * inv[1] + add[1], 0.f));
            q4.z = f2bf(fmaxf(acc[nt][2] * inv[2] + add[2], 0.f));
            q4.w = f2bf(fmaxf(acc[nt][3] * inv[3] + add[3], 0.f));
            *reinterpret_cast<ushort4*>(&qkT[((size_t)b * N_ + n) * KD + m0 + lg * 4]) = q4;
        }
    } else {
#pragma unroll
        for (int j = 0; j < 4; ++j) {
            int vch = m0 - 256 + lg * 4 + j;
            float bb = bv[vch];
#pragma unroll
            for (int nt = 0; nt < 4; ++nt) {
                int n = nx * 64 + nt * 16 + lr;
                val[((size_t)b * VD + vch) * N_ + n] = f2bf(acc[nt][j] + bb);
            }
        }
    }
}

// ------------------------------------------------------ MFMA flash attention
// 512 thr = 8 waves = 2 q-subtiles(16 rows) x 4 KV-quarters(576 keys).
// b = id&7 pins batch to XCD (id%8 round-robin) -> K/V L2-resident per XCD.
__global__ __launch_bounds__(512, 4) void attn_mfma(const ushort* __restrict__ qkT,
                                                    const ushort* __restrict__ val,
                                                    float* __restrict__ ctx) {
    __shared__ ushort Plds[8][1024];          // per-wave P, XOR-swizzled
    __shared__ float stm[8][16], stl[8][16];  // per-wave softmax stats
    __shared__ float mbuf[2][4][16][33];      // merge buffer [qsub][quarter][row][v32]

    const int id = blockIdx.x;
    const int b  = id & 7;
    const int qt = id >> 3;                  // 0..71
    const int q0 = qt * 32;
    const int w  = threadIdx.x >> 6;
    const int l  = threadIdx.x & 63;
    const int lr = l & 15, lg = l >> 4;
    const int qsub = w & 1, quarter = w >> 1;
    const int qrow0 = q0 + qsub * 16;
    const int m_lo = quarter * 576;

    const ushort* Qb = qkT + (size_t)b * N_ * KD;
    const ushort* Vb = val + (size_t)b * VD * N_;
    const ushort* qbase = Qb + (size_t)(qrow0 + lr) * KD + lg * 8;

    f32x4 O[16];
#pragma unroll
    for (int vt = 0; vt < 16; ++vt) O[vt] = (f32x4){0.f, 0.f, 0.f, 0.f};
    float mrun[4] = {-1e30f, -1e30f, -1e30f, -1e30f};
    float lrun[4] = {0.f, 0.f, 0.f, 0.f};

    ushort* Pw = &Plds[w][0];

    for (int it = 0; it < 9; ++it) {
        const int m0 = m_lo + it * 64;

        // ---- S[16n x 64m] = Q K^T (frags direct from L2-resident qkT)
        f32x4 S[4];
#pragma unroll
        for (int mt = 0; mt < 4; ++mt) S[mt] = (f32x4){0.f, 0.f, 0.f, 0.f};
        const ushort* kbase = Qb + (size_t)(m0 + lr) * KD + lg * 8;
        __builtin_amdgcn_s_setprio(1);
#pragma unroll
        for (int kc = 0; kc < 8; ++kc) {
            bf16x8 qf = *reinterpret_cast<const bf16x8*>(qbase + kc * 32);
#pragma unroll
            for (int mt = 0; mt < 4; ++mt) {
                bf16x8 kf = *reinterpret_cast<const bf16x8*>(kbase + (size_t)mt * 16 * KD + kc * 32);
                S[mt] = __builtin_amdgcn_mfma_f32_16x16x32_bf16(qf, kf, S[mt], 0, 0, 0);
            }
        }
        __builtin_amdgcn_s_setprio(0);
#pragma unroll
        for (int mt = 0; mt < 4; ++mt) S[mt] *= 0.0625f;   // 256^-0.5

        // ---- online softmax (rows n = lg*4 + r; m over 16 lanes x 4 mt)
        float corr[4];
#pragma unroll
        for (int r = 0; r < 4; ++r) {
            float mx = fmaxf(fmaxf(S[0][r], S[1][r]), fmaxf(S[2][r], S[3][r]));
#pragma unroll
            for (int off = 1; off < 16; off <<= 1) mx = fmaxf(mx, __shfl_xor(mx, off, 16));
            const float mn = fmaxf(mrun[r], mx);
            const float c  = __expf(mrun[r] - mn);
            corr[r] = c; mrun[r] = mn;
            const int row = lg * 4 + r;
            float ps = 0.f;
#pragma unroll
            for (int mt = 0; mt < 4; ++mt) {
                float p = __expf(S[mt][r] - mn);
                ps += p;
                Pw[(row * 64 + mt * 16 + lr) ^ ((row & 7) << 3)] = f2bf(p);
            }
#pragma unroll
            for (int off = 1; off < 16; off <<= 1) ps += __shfl_xor(ps, off, 16);
            lrun[r] = lrun[r] * c + ps;
        }

        // ---- rescale O
#pragma unroll
        for (int vt = 0; vt < 16; ++vt) {
            f32x4 o = O[vt];
            o[0] *= corr[0]; o[1] *= corr[1]; o[2] *= corr[2]; o[3] *= corr[3];
            O[vt] = o;
        }

        // ---- P frags back from LDS (transpose: A rows = n = lr)
        bf16x8 pf0 = *reinterpret_cast<const bf16x8*>(&Pw[(lr * 64 +  0 + lg * 8) ^ ((lr & 7) << 3)]);
        bf16x8 pf1 = *reinterpret_cast<const bf16x8*>(&Pw[(lr * 64 + 32 + lg * 8) ^ ((lr & 7) << 3)]);

        // ---- O += P V^T
        const ushort* vbase = Vb + (size_t)lr * N_ + m0 + lg * 8;
        __builtin_amdgcn_s_setprio(1);
#pragma unroll
        for (int vt = 0; vt < 16; ++vt) {
            const ushort* vrow = vbase + (size_t)vt * 16 * N_;
            bf16x8 vf0 = *reinterpret_cast<const bf16x8*>(vrow);
            bf16x8 vf1 = *reinterpret_cast<const bf16x8*>(vrow + 32);
            O[vt] = __builtin_amdgcn_mfma_f32_16x16x32_bf16(pf0, vf0, O[vt], 0, 0, 0);
            O[vt] = __builtin_amdgcn_mfma_f32_16x16x32_bf16(pf1, vf1, O[vt], 0, 0, 0);
        }
        __builtin_amdgcn_s_setprio(0);
    }

    // ---- merge 4 KV-quarter partials per q-subtile
    if (lr == 0) {
#pragma unroll
        for (int r = 0; r < 4; ++r) {
            stm[w][lg * 4 + r] = mrun[r];
            stl[w][lg * 4 + r] = lrun[r];
        }
    }
    __syncthreads();

    float scl[4];
#pragma unroll
    for (int r = 0; r < 4; ++r) {
        const int row = lg * 4 + r;
        float M = stm[qsub][row];
#pragma unroll
        for (int c = 1; c < 4; ++c) M = fmaxf(M, stm[qsub + 2 * c][row]);
        float lt = 0.f;
#pragma unroll
        for (int c = 0; c < 4; ++c)
            lt += __expf(stm[qsub + 2 * c][row] - M) * stl[qsub + 2 * c][row];
        scl[r] = __expf(mrun[r] - M) / lt;
    }

    for (int ch = 0; ch < 8; ++ch) {
#pragma unroll
        for (int v2 = 0; v2 < 2; ++v2) {
            const int vt = ch * 2 + v2;
#pragma unroll
            for (int j = 0; j < 4; ++j)
                mbuf[qsub][quarter][lg * 4 + j][v2 * 16 + lr] = O[vt][j] * scl[j];
        }
        __syncthreads();
        {
            const int row = threadIdx.x & 15;
            const int qs  = (threadIdx.x >> 4) & 1;
            const int vl  = threadIdx.x >> 5;   // 0..15
            float s0 = 0.f, s1 = 0.f;
#pragma unroll
            for (int c = 0; c < 4; ++c) {
                s0 += mbuf[qs][c][row][vl];
                s1 += mbuf[qs][c][row][vl + 16];
            }
            const int n = q0 + qs * 16 + row;
            ctx[((size_t)b * VD + ch * 32 + vl) * N_ + n] = s0;
            ctx[((size_t)b * VD + ch * 32 + vl + 16) * N_ + n] = s1;
        }
        __syncthreads();
    }
}

// ------------------------------------------ fused out conv: Z = Wf@ctx + bf
__global__ __launch_bounds__(256) void out_gemm(const float* __restrict__ Wf,
                                                const float* __restrict__ bf,
                                                const float* __restrict__ ctx,
                                                float* __restrict__ Z) {
    const int b = blockIdx.z;
    const int row0 = blockIdx.y * 64;
    const int col0 = blockIdx.x * 64;
    const float* Xb = ctx + (size_t)b * VD * N_;

    __shared__ __align__(16) float As[16][64];
    __shared__ __align__(16) float Xs[16][68];

    float acc[4][4] = {};
    const int tid = threadIdx.x;
    const int tx = tid & 15, ty = tid >> 4;
    const int tm0 = ty * 4, tn0 = tx * 4;

    for (int k0 = 0; k0 < VD; k0 += 16) {
#pragma unroll
        for (int i = 0; i < 4; ++i) {
            int idx = tid + i * 256;
            int m = idx >> 4, kk = idx & 15;
            As[kk][m] = Wf[(size_t)(row0 + m) * VD + k0 + kk];
        }
#pragma unroll
        for (int i = 0; i < 4; ++i) {
            int idx = tid + i * 256;
            int kk = idx >> 6, n = idx & 63;
            Xs[kk][n] = Xb[(size_t)(k0 + kk) * N_ + col0 + n];
        }
        __syncthreads();
#pragma unroll
        for (int kk = 0; kk < 16; ++kk) {
            float4 a4 = *reinterpret_cast<const float4*>(&As[kk][tm0]);
            float4 x4 = *reinterpret_cast<const float4*>(&Xs[kk][tn0]);
            float a[4] = {a4.x, a4.y, a4.z, a4.w};
            float xv[4] = {x4.x, x4.y, x4.z, x4.w};
#pragma unroll
            for (int i = 0; i < 4; ++i)
#pragma unroll
                for (int j = 0; j < 4; ++j)
                    acc[i][j] = fmaf(a[i], xv[j], acc[i][j]);
        }
        __syncthreads();
    }

#pragma unroll
    for (int i = 0; i < 4; ++i) {
        int o = row0 + tm0 + i;
        float bb = bf[o];
        float* dst = Z + ((size_t)b * OD + o) * N_ + col0 + tn0;
#pragma unroll
        for (int j = 0; j < 4; ++j) dst[j] = acc[i][j] + bb;
    }
}

// --------------------------- bilinear upsample (align_corners) + BN + ReLU
__global__ void upsample_kernel(const float* __restrict__ Z,
                                const float* __restrict__ rg, const float* __restrict__ rb,
                                const float* __restrict__ rm, const float* __restrict__ rv,
                                float* __restrict__ out) {
    const int total = B_ * OD * H_ * W_;
    const float s = 47.0f / 95.0f;   // (HP-1)/(H-1), align_corners=True
    for (int idx = blockIdx.x * blockDim.x + threadIdx.x; idx < total;
         idx += gridDim.x * blockDim.x) {
        int x = idx % W_;
        int t = idx / W_;
        int y = t % H_;
        int bo = t / H_;
        int o = bo % OD;
        float fy = y * s, fx = x * s;
        int y0 = (int)fy, x0 = (int)fx;
        int y1 = min(y0 + 1, HP - 1), x1 = min(x0 + 1, WP - 1);
        float wy = fy - y0, wx = fx - x0;
        const float* Zp = Z + (size_t)bo * N_;
        float v00 = Zp[y0 * WP + x0], v01 = Zp[y0 * WP + x1];
        float v10 = Zp[y1 * WP + x0], v11 = Zp[y1 * WP + x1];
        float r0 = v00 + (v01 - v00) * wx;
        float r1 = v10 + (v11 - v10) * wx;
        float v = r0 + (r1 - r0) * wy;
        float inv = rg[o] * rsqrtf(rv[o] + EPSV);
        float add = rb[o] - rm[o] * inv;
        out[idx] = fmaxf(v * inv + add, 0.f);
    }
}

extern "C" void kernel_launch(void* const* d_in, const int* in_sizes, int n_in,
                              void* d_out, int out_size, void* d_ws, size_t ws_size,
                              hipStream_t stream) {
    const float* x  = (const float*)d_in[0];
    const float* Wk = (const float*)d_in[1];
    const float* kg = (const float*)d_in[2];
    const float* kb = (const float*)d_in[3];
    const float* km = (const float*)d_in[4];
    const float* kvv= (const float*)d_in[5];
    const float* Wv = (const float*)d_in[6];
    const float* bv = (const float*)d_in[7];
    const float* Ww = (const float*)d_in[8];
    const float* bw = (const float*)d_in[9];
    const float* Wr = (const float*)d_in[10];
    const float* rg = (const float*)d_in[11];
    const float* rb = (const float*)d_in[12];
    const float* rm = (const float*)d_in[13];
    const float* rv = (const float*)d_in[14];

    char* wsb = (char*)d_ws;
    ushort* xpT  = (ushort*)(wsb + BOFF_XPT);
    ushort* qkT  = (ushort*)(wsb + BOFF_QKT);
    ushort* valp = (ushort*)(wsb + BOFF_VAL);
    float*  ctx  = (float*)(wsb + BOFF_CTX);
    ushort* W2   = (ushort*)(wsb + BOFF_W2);
    float*  Wf   = (float*)(wsb + BOFF_WF);
    float*  bfb  = (float*)(wsb + BOFF_BF);
    float*  Z    = (float*)(wsb + BOFF_XPT);  // overlays xpT+qkT+val (dead)
    float*  out  = (float*)d_out;

    pool_t_kernel<<<8 * 48 * 8, 192, 0, stream>>>(x, xpT);
    w2_kernel<<<512, 256, 0, stream>>>(Wk, Wv, W2);
    fuse_w_kernel<<<OD, 256, 0, stream>>>(Wr, Ww, Wf);
    fuse_bias_kernel<<<2, 256, 0, stream>>>(Wr, bw, bfb);
    qkv_mfma<<<2304, 256, 0, stream>>>(W2, xpT, kg, kb, km, kvv, bv, qkT, valp);
    attn_mfma<<<576, 512, 0, stream>>>(qkT, valp, ctx);
    out_gemm<<<dim3(N_ / 64, OD / 64, B_), 256, 0, stream>>>(Wf, bfb, ctx, Z);
    upsample_kernel<<<4096, 256, 0, stream>>>(Z, rg, rb, rm, rv, out);
}

// Round 4
// 433.378 us; speedup vs baseline: 32.2077x; 1.9462x over previous
//
#include <hip/hip_runtime.h>
#include <math.h>

typedef __attribute__((ext_vector_type(8))) short bf16x8;
typedef __attribute__((ext_vector_type(4))) float f32x4;

namespace {

constexpr int B_ = 8, C_ = 512, H_ = 96, W_ = 96;
constexpr int HP = 48, WP = 48, N_ = HP * WP;   // pooled spatial, N=2304
constexpr int KD = 256, VD = 256, OD = 512;
constexpr float EPSV = 1e-5f;

// workspace byte offsets
constexpr size_t BOFF_XPT = 0;                                       // bf16 [B][N][C]
constexpr size_t BOFF_QKT = BOFF_XPT + (size_t)B_ * N_ * C_ * 2;     // bf16 [B][N][KD]
constexpr size_t BOFF_VAL = BOFF_QKT + (size_t)B_ * N_ * KD * 2;     // bf16 [B][VD][N]
constexpr size_t BOFF_CTX = BOFF_VAL + (size_t)B_ * VD * N_ * 2;     // bf16 [B][N][VD]
constexpr size_t BOFF_W2  = BOFF_CTX + (size_t)B_ * N_ * VD * 2;     // bf16 [512][512]
constexpr size_t BOFF_WF  = BOFF_W2  + (size_t)512 * 512 * 2;        // bf16 [OD][VD]
constexpr size_t BOFF_BF  = BOFF_WF  + (size_t)OD * VD * 2;          // fp32 [OD]
// Z fp32 [B][OD][N] (37.7MB) overlays [xpT+qkT+val] (exactly 37.7MB), dead by then

} // namespace

__device__ __forceinline__ ushort f2bf(float f) {
    union { float f; unsigned u; } x; x.f = f;
    unsigned r = x.u + 0x7FFFu + ((x.u >> 16) & 1u);
    return (ushort)(r >> 16);
}

__device__ __forceinline__ void gload_lds16(const void* g, void* l) {
    __builtin_amdgcn_global_load_lds(
        (const __attribute__((address_space(1))) unsigned int*)g,
        (__attribute__((address_space(3))) unsigned int*)l, 16, 0, 0);
}

// ------------------------ fused maxpool 2x2 + transpose + bf16: x -> xpT[b][n][c]
__global__ __launch_bounds__(192) void pool_t_kernel(const float* __restrict__ x,
                                                     ushort* __restrict__ xpT) {
    __shared__ float ps[64][49];
    const int gid = blockIdx.x;
    const int ct = gid & 7;          // c-tile (64 channels)
    const int tmp = gid >> 3;
    const int oh = tmp % 48;
    const int b  = tmp / 48;
    const int t = threadIdx.x;
    const int ow = t % 48, ci = t / 48;   // ci 0..3

    const int c0 = ct * 64;
#pragma unroll
    for (int pass = 0; pass < 16; ++pass) {
        const int c = pass * 4 + ci;
        const float* px = x + (((size_t)b * C_ + c0 + c) * H_ + 2 * oh) * W_ + 2 * ow;
        float2 a = *reinterpret_cast<const float2*>(px);
        float2 d = *reinterpret_cast<const float2*>(px + W_);
        ps[c][ow] = fmaxf(fmaxf(a.x, a.y), fmaxf(d.x, d.y));
    }
    __syncthreads();
    const int cc = t & 63;
    const int nr0 = t >> 6;          // 0..2
#pragma unroll
    for (int pass = 0; pass < 16; ++pass) {
        const int nr = pass * 3 + nr0;     // 0..47
        xpT[((size_t)b * N_ + oh * 48 + nr) * C_ + c0 + cc] = f2bf(ps[cc][nr]);
    }
}

// ------------------------------------ pack Wk|Wv into bf16 W2 [512][512]
__global__ __launch_bounds__(256) void w2_kernel(const float* __restrict__ Wk,
                                                 const float* __restrict__ Wv,
                                                 ushort* __restrict__ W2) {
    const int m = blockIdx.x;        // 0..511
    const float* src = (m < 256) ? (Wk + (size_t)m * 512) : (Wv + (size_t)(m - 256) * 512);
    const int k = threadIdx.x * 2;
    float2 v = *reinterpret_cast<const float2*>(src + k);
    ushort2 p; p.x = f2bf(v.x); p.y = f2bf(v.y);
    *reinterpret_cast<ushort2*>(&W2[(size_t)m * 512 + k]) = p;
}

// ------------------------------------------------- weight fusion: Wfb = bf16(Wr@Ww)
__global__ __launch_bounds__(256) void fuse_w_kernel(const float* __restrict__ Wr,
                                                     const float* __restrict__ Ww,
                                                     ushort* __restrict__ Wfb) {
    int o = blockIdx.x;    // 0..511
    int v = threadIdx.x;   // 0..255
    float s = 0.f;
    for (int c = 0; c < OD; ++c)
        s = fmaf(Wr[(size_t)o * OD + c], Ww[(size_t)c * VD + v], s);
    Wfb[(size_t)o * VD + v] = f2bf(s);
}

__global__ void fuse_bias_kernel(const float* __restrict__ Wr,
                                 const float* __restrict__ bw,
                                 float* __restrict__ bf) {
    int o = blockIdx.x * blockDim.x + threadIdx.x;
    if (o < OD) {
        float s = 0.f;
        for (int c = 0; c < OD; ++c) s = fmaf(Wr[(size_t)o * OD + c], bw[c], s);
        bf[o] = s;
    }
}

// ------------------------------------- qkv MFMA GEMM: [Wk|Wv] @ xpT^T
__global__ __launch_bounds__(256) void qkv_mfma(
    const ushort* __restrict__ W2, const ushort* __restrict__ xpT,
    const float* __restrict__ kg, const float* __restrict__ kb,
    const float* __restrict__ km, const float* __restrict__ kv,
    const float* __restrict__ bv,
    ushort* __restrict__ qkT, ushort* __restrict__ val) {
    const int id = blockIdx.x;
    const int b = id & 7;
    const int t = id >> 3;           // 0..287
    const int my = t & 7;            // m-tile
    const int nx = t >> 3;           // 0..35
    const int w = threadIdx.x >> 6, l = threadIdx.x & 63;
    const int lr = l & 15, lg = l >> 4;

    const ushort* Xb = xpT + (size_t)b * N_ * C_;
    const int m0 = my * 64 + w * 16;
    const ushort* Arow = W2 + (size_t)(m0 + lr) * 512 + lg * 8;
    const ushort* Brow = Xb + (size_t)(nx * 64 + lr) * 512 + lg * 8;

    f32x4 acc[4];
#pragma unroll
    for (int nt = 0; nt < 4; ++nt) acc[nt] = (f32x4){0.f, 0.f, 0.f, 0.f};

#pragma unroll
    for (int kc = 0; kc < 16; ++kc) {
        bf16x8 af = *reinterpret_cast<const bf16x8*>(Arow + kc * 32);
#pragma unroll
        for (int nt = 0; nt < 4; ++nt) {
            bf16x8 bfr = *reinterpret_cast<const bf16x8*>(Brow + (size_t)nt * 16 * 512 + kc * 32);
            acc[nt] = __builtin_amdgcn_mfma_f32_16x16x32_bf16(af, bfr, acc[nt], 0, 0, 0);
        }
    }

    if (m0 < 256) {
        float inv[4], add[4];
#pragma unroll
        for (int j = 0; j < 4; ++j) {
            int o = m0 + lg * 4 + j;
            inv[j] = kg[o] * rsqrtf(kv[o] + EPSV);
            add[j] = kb[o] - km[o] * inv[j];
        }
#pragma unroll
        for (int nt = 0; nt < 4; ++nt) {
            int n = nx * 64 + nt * 16 + lr;
            ushort4 q4;
            q4.x = f2bf(fmaxf(acc[nt][0] * inv[0] + add[0], 0.f));
            q4.y = f2bf(fmaxf(acc[nt][1] * inv[1] + add[1], 0.f));
            q4.z = f2bf(fmaxf(acc[nt][2] * inv[2] + add[2], 0.f));
            q4.w = f2bf(fmaxf(acc[nt][3] * inv[3] + add[3], 0.f));
            *reinterpret_cast<ushort4*>(&qkT[((size_t)b * N_ + n) * KD + m0 + lg * 4]) = q4;
        }
    } else {
#pragma unroll
        for (int j = 0; j < 4; ++j) {
            int vch = m0 - 256 + lg * 4 + j;
            float bb = bv[vch];
#pragma unroll
            for (int nt = 0; nt < 4; ++nt) {
                int n = nx * 64 + nt * 16 + lr;
                val[((size_t)b * VD + vch) * N_ + n] = f2bf(acc[nt][j] + bb);
            }
        }
    }
}

// ------------------------------------------------------ LDS-staged MFMA flash attention
// 256 thr / 4 waves; 64 q-rows per block; m-loop: 72 tiles of 32 keys.
// K/V tiles DMA'd via global_load_lds (double-buffered, counted vmcnt),
// XOR-swizzled via pre-swizzled global source (linear LDS dest).
__global__ __launch_bounds__(256, 2) void attn_mfma(const ushort* __restrict__ qkT,
                                                    const ushort* __restrict__ val,
                                                    ushort* __restrict__ ctxT) {
    __shared__ ushort Kl[2][8192];   // [kc 8][m 32][32 kd] per buf, 64B-row subtiles
    __shared__ ushort Vl[2][8192];   // [v 256][m 32] per buf
    __shared__ ushort Pl[4][512];    // per-wave P [16 q][32 m]

    const int id = blockIdx.x;
    const int b  = id & 7;           // XCD-pinned batch
    const int qt = id >> 3;          // 0..35
    const int q0 = qt * 64;
    const int w  = threadIdx.x >> 6;
    const int l  = threadIdx.x & 63;
    const int lr = l & 15, lg = l >> 4;

    const ushort* Qb = qkT + (size_t)b * N_ * KD;
    const ushort* Vb = val + (size_t)b * VD * N_;

    // shared per-lane swizzled read base (u16 units) for K/V/P 64B-row subtiles
    const int rb = lr * 32 + ((lg * 8) ^ (((lr >> 1) & 3) << 3));

    // resident Q fragments: rows q0 + w*16 + lr, all KD
    bf16x8 qf[8];
    {
        const ushort* qrow = Qb + (size_t)(q0 + w * 16 + lr) * KD + lg * 8;
#pragma unroll
        for (int kc = 0; kc < 8; ++kc)
            qf[kc] = *reinterpret_cast<const bf16x8*>(qrow + kc * 32);
    }
    asm volatile("s_waitcnt vmcnt(0)" ::: "memory");

    // DMA one 32-key tile (K 16KB + V 16KB = 8 wave-issues)
    auto stage = [&](int itx, int buf) {
#pragma unroll
        for (int j = 0; j < 4; ++j) {
            const int prow = j * 64 + w * 16 + (l >> 2);   // 0..255 = kc*32 + m
            const int m = prow & 31;
            const int kc = prow >> 5;
            const int cb = ((l & 3) * 16) ^ (((m >> 1) & 3) << 4);
            const char* src = (const char*)Qb + (size_t)(itx * 32 + m) * (KD * 2) + kc * 64 + cb;
            gload_lds16(src, (char*)(&Kl[buf][0]) + j * 4096 + w * 1024);
        }
#pragma unroll
        for (int j = 0; j < 4; ++j) {
            const int r = j * 64 + w * 16 + (l >> 2);      // v-row 0..255
            const int cb = ((l & 3) * 16) ^ (((r >> 1) & 3) << 4);
            const char* src = (const char*)Vb + (size_t)r * (N_ * 2) + itx * 64 + cb;
            gload_lds16(src, (char*)(&Vl[buf][0]) + j * 4096 + w * 1024);
        }
    };

    stage(0, 0);
    stage(1, 1);

    f32x4 O[16];
#pragma unroll
    for (int vt = 0; vt < 16; ++vt) O[vt] = (f32x4){0.f, 0.f, 0.f, 0.f};
    float mrun[4] = {-1e30f, -1e30f, -1e30f, -1e30f};
    float lrun[4] = {0.f, 0.f, 0.f, 0.f};
    ushort* Pw = &Pl[w][0];

    for (int it = 0; it < 72; ++it) {
        const int cur = it & 1;
        if (it < 70) { asm volatile("s_waitcnt vmcnt(8)" ::: "memory"); }
        else         { asm volatile("s_waitcnt vmcnt(0)" ::: "memory"); }
        __builtin_amdgcn_s_barrier();
        __builtin_amdgcn_sched_barrier(0);

        const ushort* Kc = &Kl[cur][0];
        const ushort* Vc = &Vl[cur][0];

        // ---- S[16q x 32m] = Q K^T
        f32x4 S0 = (f32x4){0.f, 0.f, 0.f, 0.f};
        f32x4 S1 = (f32x4){0.f, 0.f, 0.f, 0.f};
        __builtin_amdgcn_s_setprio(1);
#pragma unroll
        for (int kc = 0; kc < 8; ++kc) {
            bf16x8 k0 = *reinterpret_cast<const bf16x8*>(Kc + kc * 1024 + rb);
            bf16x8 k1 = *reinterpret_cast<const bf16x8*>(Kc + kc * 1024 + 512 + rb);
            S0 = __builtin_amdgcn_mfma_f32_16x16x32_bf16(qf[kc], k0, S0, 0, 0, 0);
            S1 = __builtin_amdgcn_mfma_f32_16x16x32_bf16(qf[kc], k1, S1, 0, 0, 0);
        }
        __builtin_amdgcn_s_setprio(0);

        // ---- online softmax (row q = lg*4+r; m over 16 lanes x 2)
        float corr[4];
#pragma unroll
        for (int r = 0; r < 4; ++r) {
            float s0 = S0[r] * 0.0625f, s1 = S1[r] * 0.0625f;
            float mx = fmaxf(s0, s1);
#pragma unroll
            for (int off = 1; off < 16; off <<= 1) mx = fmaxf(mx, __shfl_xor(mx, off, 16));
            const float mn = fmaxf(mrun[r], mx);
            const float c  = __expf(mrun[r] - mn);
            const float p0 = __expf(s0 - mn), p1 = __expf(s1 - mn);
            corr[r] = c; mrun[r] = mn;
            float ps = p0 + p1;
#pragma unroll
            for (int off = 1; off < 16; off <<= 1) ps += __shfl_xor(ps, off, 16);
            lrun[r] = lrun[r] * c + ps;
            const int row = lg * 4 + r;
            const int sw = ((row >> 1) & 3) << 3;
            Pw[row * 32 + (lr ^ sw)] = f2bf(p0);
            Pw[row * 32 + ((16 + lr) ^ sw)] = f2bf(p1);
        }

        // ---- rescale O
#pragma unroll
        for (int vt = 0; vt < 16; ++vt) {
            f32x4 o = O[vt];
            o[0] *= corr[0]; o[1] *= corr[1]; o[2] *= corr[2]; o[3] *= corr[3];
            O[vt] = o;
        }

        // ---- O += P V^T
        bf16x8 pf = *reinterpret_cast<const bf16x8*>(Pw + rb);
        __builtin_amdgcn_s_setprio(1);
#pragma unroll
        for (int vt = 0; vt < 16; ++vt) {
            bf16x8 vf = *reinterpret_cast<const bf16x8*>(Vc + vt * 512 + rb);
            O[vt] = __builtin_amdgcn_mfma_f32_16x16x32_bf16(pf, vf, O[vt], 0, 0, 0);
        }
        __builtin_amdgcn_s_setprio(0);

        __builtin_amdgcn_sched_barrier(0);
        __builtin_amdgcn_s_barrier();       // all waves done reading buf[cur]
        if (it < 70) stage(it + 2, cur);
    }

    // ---- epilogue: normalize, store ctxT bf16 [b][n][v]
    float il[4];
#pragma unroll
    for (int r = 0; r < 4; ++r) il[r] = 1.0f / lrun[r];
    ushort* Cb = ctxT + ((size_t)b * N_ + q0 + w * 16) * VD;
#pragma unroll
    for (int vt = 0; vt < 16; ++vt) {
#pragma unroll
        for (int j = 0; j < 4; ++j)
            Cb[(size_t)(lg * 4 + j) * VD + vt * 16 + lr] = f2bf(O[vt][j] * il[j]);
    }
}

// ------------------------------------------ out conv MFMA: Z = Wfb@ctxT^T + bf
__global__ __launch_bounds__(256) void out_mfma(const ushort* __restrict__ Wfb,
                                                const float* __restrict__ bf,
                                                const ushort* __restrict__ ctxT,
                                                float* __restrict__ Z) {
    const int id = blockIdx.x;
    const int b = id & 7;
    const int t = id >> 3;           // 0..287
    const int my = t & 7;            // OD tile
    const int nx = t >> 3;           // 0..35
    const int w = threadIdx.x >> 6, l = threadIdx.x & 63;
    const int lr = l & 15, lg = l >> 4;

    const int m0 = my * 64 + w * 16;
    const ushort* Arow = Wfb + (size_t)(m0 + lr) * VD + lg * 8;
    const ushort* Brow = ctxT + ((size_t)b * N_ + nx * 64 + lr) * VD + lg * 8;

    f32x4 acc[4];
#pragma unroll
    for (int nt = 0; nt < 4; ++nt) acc[nt] = (f32x4){0.f, 0.f, 0.f, 0.f};

#pragma unroll
    for (int kc = 0; kc < 8; ++kc) {
        bf16x8 af = *reinterpret_cast<const bf16x8*>(Arow + kc * 32);
#pragma unroll
        for (int nt = 0; nt < 4; ++nt) {
            bf16x8 bfr = *reinterpret_cast<const bf16x8*>(Brow + (size_t)nt * 16 * VD + kc * 32);
            acc[nt] = __builtin_amdgcn_mfma_f32_16x16x32_bf16(af, bfr, acc[nt], 0, 0, 0);
        }
    }

#pragma unroll
    for (int j = 0; j < 4; ++j) {
        const int o = m0 + lg * 4 + j;
        const float bb = bf[o];
#pragma unroll
        for (int nt = 0; nt < 4; ++nt) {
            const int n = nx * 64 + nt * 16 + lr;
            Z[((size_t)b * OD + o) * N_ + n] = acc[nt][j] + bb;
        }
    }
}

// --------------------------- bilinear upsample (align_corners) + BN + ReLU
__global__ void upsample_kernel(const float* __restrict__ Z,
                                const float* __restrict__ rg, const float* __restrict__ rb,
                                const float* __restrict__ rm, const float* __restrict__ rv,
                                float* __restrict__ out) {
    const int total = B_ * OD * H_ * W_;
    const float s = 47.0f / 95.0f;   // (HP-1)/(H-1), align_corners=True
    for (int idx = blockIdx.x * blockDim.x + threadIdx.x; idx < total;
         idx += gridDim.x * blockDim.x) {
        int x = idx % W_;
        int t = idx / W_;
        int y = t % H_;
        int bo = t / H_;
        int o = bo % OD;
        float fy = y * s, fx = x * s;
        int y0 = (int)fy, x0 = (int)fx;
        int y1 = min(y0 + 1, HP - 1), x1 = min(x0 + 1, WP - 1);
        float wy = fy - y0, wx = fx - x0;
        const float* Zp = Z + (size_t)bo * N_;
        float v00 = Zp[y0 * WP + x0], v01 = Zp[y0 * WP + x1];
        float v10 = Zp[y1 * WP + x0], v11 = Zp[y1 * WP + x1];
        float r0 = v00 + (v01 - v00) * wx;
        float r1 = v10 + (v11 - v10) * wx;
        float v = r0 + (r1 - r0) * wy;
        float inv = rg[o] * rsqrtf(rv[o] + EPSV);
        float add = rb[o] - rm[o] * inv;
        out[idx] = fmaxf(v * inv + add, 0.f);
    }
}

extern "C" void kernel_launch(void* const* d_in, const int* in_sizes, int n_in,
                              void* d_out, int out_size, void* d_ws, size_t ws_size,
                              hipStream_t stream) {
    const float* x  = (const float*)d_in[0];
    const float* Wk = (const float*)d_in[1];
    const float* kg = (const float*)d_in[2];
    const float* kb = (const float*)d_in[3];
    const float* km = (const float*)d_in[4];
    const float* kvv= (const float*)d_in[5];
    const float* Wv = (const float*)d_in[6];
    const float* bv = (const float*)d_in[7];
    const float* Ww = (const float*)d_in[8];
    const float* bw = (const float*)d_in[9];
    const float* Wr = (const float*)d_in[10];
    const float* rg = (const float*)d_in[11];
    const float* rb = (const float*)d_in[12];
    const float* rm = (const float*)d_in[13];
    const float* rv = (const float*)d_in[14];

    char* wsb = (char*)d_ws;
    ushort* xpT  = (ushort*)(wsb + BOFF_XPT);
    ushort* qkT  = (ushort*)(wsb + BOFF_QKT);
    ushort* valp = (ushort*)(wsb + BOFF_VAL);
    ushort* ctxT = (ushort*)(wsb + BOFF_CTX);
    ushort* W2   = (ushort*)(wsb + BOFF_W2);
    ushort* Wfb  = (ushort*)(wsb + BOFF_WF);
    float*  bfb  = (float*)(wsb + BOFF_BF);
    float*  Z    = (float*)(wsb + BOFF_XPT);  // overlays xpT+qkT+val (dead)
    float*  out  = (float*)d_out;

    pool_t_kernel<<<8 * 48 * 8, 192, 0, stream>>>(x, xpT);
    w2_kernel<<<512, 256, 0, stream>>>(Wk, Wv, W2);
    fuse_w_kernel<<<OD, 256, 0, stream>>>(Wr, Ww, Wfb);
    fuse_bias_kernel<<<2, 256, 0, stream>>>(Wr, bw, bfb);
    qkv_mfma<<<2304, 256, 0, stream>>>(W2, xpT, kg, kb, km, kvv, bv, qkT, valp);
    attn_mfma<<<288, 256, 0, stream>>>(qkT, valp, ctxT);
    out_mfma<<<2304, 256, 0, stream>>>(Wfb, bfb, ctxT, Z);
    upsample_kernel<<<4096, 256, 0, stream>>>(Z, rg, rb, rm, rv, out);
}

// Round 5
// 430.224 us; speedup vs baseline: 32.4439x; 1.0073x over previous
//
#include <hip/hip_runtime.h>
#include <math.h>

typedef __attribute__((ext_vector_type(8))) short bf16x8;
typedef __attribute__((ext_vector_type(4))) float f32x4;

namespace {

constexpr int B_ = 8, C_ = 512, H_ = 96, W_ = 96;
constexpr int HP = 48, WP = 48, N_ = HP * WP;   // pooled spatial, N=2304
constexpr int KD = 256, VD = 256, OD = 512;
constexpr float EPSV = 1e-5f;

// workspace byte offsets
constexpr size_t BOFF_XPT = 0;                                       // bf16 [B][N][C]
constexpr size_t BOFF_QKT = BOFF_XPT + (size_t)B_ * N_ * C_ * 2;     // bf16 [B][N][KD]
constexpr size_t BOFF_VAL = BOFF_QKT + (size_t)B_ * N_ * KD * 2;     // bf16 [B][VD][N]
constexpr size_t BOFF_CTX = BOFF_VAL + (size_t)B_ * VD * N_ * 2;     // bf16 [B][N][VD]
constexpr size_t BOFF_W2  = BOFF_CTX + (size_t)B_ * N_ * VD * 2;     // bf16 [512][512]
constexpr size_t BOFF_WF  = BOFF_W2  + (size_t)512 * 512 * 2;        // bf16 [OD][VD]
constexpr size_t BOFF_BF  = BOFF_WF  + (size_t)OD * VD * 2;          // fp32 [OD]
// Z bf16 [B][OD][N] (18.9MB) overlays xpT (18.9MB), dead by then

} // namespace

__device__ __forceinline__ ushort f2bf(float f) {
    union { float f; unsigned u; } x; x.f = f;
    unsigned r = x.u + 0x7FFFu + ((x.u >> 16) & 1u);
    return (ushort)(r >> 16);
}

__device__ __forceinline__ float bf2f(ushort u) {
    union { unsigned u; float f; } x; x.u = ((unsigned)u) << 16;
    return x.f;
}

__device__ __forceinline__ void gload_lds16(const void* g, void* l) {
    __builtin_amdgcn_global_load_lds(
        (const __attribute__((address_space(1))) unsigned int*)g,
        (__attribute__((address_space(3))) unsigned int*)l, 16, 0, 0);
}

// ------------------------ fused maxpool 2x2 + transpose + bf16: x -> xpT[b][n][c]
__global__ __launch_bounds__(192) void pool_t_kernel(const float* __restrict__ x,
                                                     ushort* __restrict__ xpT) {
    __shared__ float ps[64][49];
    const int gid = blockIdx.x;
    const int ct = gid & 7;          // c-tile (64 channels)
    const int tmp = gid >> 3;
    const int oh = tmp % 48;
    const int b  = tmp / 48;
    const int t = threadIdx.x;
    const int ow = t % 48, ci = t / 48;   // ci 0..3

    const int c0 = ct * 64;
#pragma unroll
    for (int pass = 0; pass < 16; ++pass) {
        const int c = pass * 4 + ci;
        const float* px = x + (((size_t)b * C_ + c0 + c) * H_ + 2 * oh) * W_ + 2 * ow;
        float2 a = *reinterpret_cast<const float2*>(px);
        float2 d = *reinterpret_cast<const float2*>(px + W_);
        ps[c][ow] = fmaxf(fmaxf(a.x, a.y), fmaxf(d.x, d.y));
    }
    __syncthreads();
    const int cc = t & 63;
    const int nr0 = t >> 6;          // 0..2
#pragma unroll
    for (int pass = 0; pass < 16; ++pass) {
        const int nr = pass * 3 + nr0;     // 0..47
        xpT[((size_t)b * N_ + oh * 48 + nr) * C_ + c0 + cc] = f2bf(ps[cc][nr]);
    }
}

// ------------------------------------ pack Wk|Wv into bf16 W2 [512][512]
__global__ __launch_bounds__(256) void w2_kernel(const float* __restrict__ Wk,
                                                 const float* __restrict__ Wv,
                                                 ushort* __restrict__ W2) {
    const int m = blockIdx.x;        // 0..511
    const float* src = (m < 256) ? (Wk + (size_t)m * 512) : (Wv + (size_t)(m - 256) * 512);
    const int k = threadIdx.x * 2;
    float2 v = *reinterpret_cast<const float2*>(src + k);
    ushort2 p; p.x = f2bf(v.x); p.y = f2bf(v.y);
    *reinterpret_cast<ushort2*>(&W2[(size_t)m * 512 + k]) = p;
}

// ------------------------------------------------- weight fusion: Wfb = bf16(Wr@Ww)
__global__ __launch_bounds__(256) void fuse_w_kernel(const float* __restrict__ Wr,
                                                     const float* __restrict__ Ww,
                                                     ushort* __restrict__ Wfb) {
    int o = blockIdx.x;    // 0..511
    int v = threadIdx.x;   // 0..255
    float s = 0.f;
    for (int c = 0; c < OD; ++c)
        s = fmaf(Wr[(size_t)o * OD + c], Ww[(size_t)c * VD + v], s);
    Wfb[(size_t)o * VD + v] = f2bf(s);
}

__global__ void fuse_bias_kernel(const float* __restrict__ Wr,
                                 const float* __restrict__ bw,
                                 float* __restrict__ bf) {
    int o = blockIdx.x * blockDim.x + threadIdx.x;
    if (o < OD) {
        float s = 0.f;
        for (int c = 0; c < OD; ++c) s = fmaf(Wr[(size_t)o * OD + c], bw[c], s);
        bf[o] = s;
    }
}

// ------------------------------------- qkv MFMA GEMM: [Wk|Wv] @ xpT^T
__global__ __launch_bounds__(256) void qkv_mfma(
    const ushort* __restrict__ W2, const ushort* __restrict__ xpT,
    const float* __restrict__ kg, const float* __restrict__ kb,
    const float* __restrict__ km, const float* __restrict__ kv,
    const float* __restrict__ bv,
    ushort* __restrict__ qkT, ushort* __restrict__ val) {
    const int id = blockIdx.x;
    const int b = id & 7;
    const int t = id >> 3;           // 0..287
    const int my = t & 7;            // m-tile
    const int nx = t >> 3;           // 0..35
    const int w = threadIdx.x >> 6, l = threadIdx.x & 63;
    const int lr = l & 15, lg = l >> 4;

    const ushort* Xb = xpT + (size_t)b * N_ * C_;
    const int m0 = my * 64 + w * 16;
    const ushort* Arow = W2 + (size_t)(m0 + lr) * 512 + lg * 8;
    const ushort* Brow = Xb + (size_t)(nx * 64 + lr) * 512 + lg * 8;

    f32x4 acc[4];
#pragma unroll
    for (int nt = 0; nt < 4; ++nt) acc[nt] = (f32x4){0.f, 0.f, 0.f, 0.f};

#pragma unroll
    for (int kc = 0; kc < 16; ++kc) {
        bf16x8 af = *reinterpret_cast<const bf16x8*>(Arow + kc * 32);
#pragma unroll
        for (int nt = 0; nt < 4; ++nt) {
            bf16x8 bfr = *reinterpret_cast<const bf16x8*>(Brow + (size_t)nt * 16 * 512 + kc * 32);
            acc[nt] = __builtin_amdgcn_mfma_f32_16x16x32_bf16(af, bfr, acc[nt], 0, 0, 0);
        }
    }

    if (m0 < 256) {
        float inv[4], add[4];
#pragma unroll
        for (int j = 0; j < 4; ++j) {
            int o = m0 + lg * 4 + j;
            inv[j] = kg[o] * rsqrtf(kv[o] + EPSV);
            add[j] = kb[o] - km[o] * inv[j];
        }
#pragma unroll
        for (int nt = 0; nt < 4; ++nt) {
            int n = nx * 64 + nt * 16 + lr;
            ushort4 q4;
            q4.x = f2bf(fmaxf(acc[nt][0] * inv[0] + add[0], 0.f));
            q4.y = f2bf(fmaxf(acc[nt][1] * inv[1] + add[1], 0.f));
            q4.z = f2bf(fmaxf(acc[nt][2] * inv[2] + add[2], 0.f));
            q4.w = f2bf(fmaxf(acc[nt][3] * inv[3] + add[3], 0.f));
            *reinterpret_cast<ushort4*>(&qkT[((size_t)b * N_ + n) * KD + m0 + lg * 4]) = q4;
        }
    } else {
#pragma unroll
        for (int j = 0; j < 4; ++j) {
            int vch = m0 - 256 + lg * 4 + j;
            float bb = bv[vch];
#pragma unroll
            for (int nt = 0; nt < 4; ++nt) {
                int n = nx * 64 + nt * 16 + lr;
                val[((size_t)b * VD + vch) * N_ + n] = f2bf(acc[nt][j] + bb);
            }
        }
    }
}

// ------------------------------------------------------ LDS-staged MFMA flash attention
// 256 thr / 4 waves; 64 q-rows/block; 72 tiles of 32 keys.
// K double-buffered, V single-buffered (staged post-PV-barrier) -> 52KB LDS,
// 3 blocks/CU: all 288 blocks co-resident. l tracked via ones-MFMA; defer-max.
__global__ __launch_bounds__(256, 3) void attn_mfma(const ushort* __restrict__ qkT,
                                                    const ushort* __restrict__ val,
                                                    ushort* __restrict__ ctxT) {
    __shared__ ushort Kl[2][8192];   // 2 x 16KB: [kc 8][m 32][32 kd]
    __shared__ ushort Vl[8192];      // 16KB: [v 256][m 32]
    __shared__ ushort Pl[4][512];    // per-wave P [16 q][32 m]

    const int id = blockIdx.x;
    const int b  = id & 7;           // XCD-pinned batch
    const int qt = id >> 3;          // 0..35
    const int q0 = qt * 64;
    const int w  = threadIdx.x >> 6;
    const int l  = threadIdx.x & 63;
    const int lr = l & 15, lg = l >> 4;

    const ushort* Qb = qkT + (size_t)b * N_ * KD;
    const ushort* Vb = val + (size_t)b * VD * N_;

    // shared per-lane swizzled read base (u16 units) for K/V/P 64B-row subtiles
    const int rb = lr * 32 + ((lg * 8) ^ (((lr >> 1) & 3) << 3));

    // resident Q fragments
    bf16x8 qf[8];
    {
        const ushort* qrow = Qb + (size_t)(q0 + w * 16 + lr) * KD + lg * 8;
#pragma unroll
        for (int kc = 0; kc < 8; ++kc)
            qf[kc] = *reinterpret_cast<const bf16x8*>(qrow + kc * 32);
    }
    asm volatile("s_waitcnt vmcnt(0)" ::: "memory");

    auto stage_K = [&](int itx, int buf) {
#pragma unroll
        for (int j = 0; j < 4; ++j) {
            const int prow = j * 64 + w * 16 + (l >> 2);   // kc*32 + m
            const int m = prow & 31;
            const int kc = prow >> 5;
            const int cb = ((l & 3) * 16) ^ (((m >> 1) & 3) << 4);
            const char* src = (const char*)Qb + (size_t)(itx * 32 + m) * (KD * 2) + kc * 64 + cb;
            gload_lds16(src, (char*)(&Kl[buf][0]) + j * 4096 + w * 1024);
        }
    };
    auto stage_V = [&](int itx) {
#pragma unroll
        for (int j = 0; j < 4; ++j) {
            const int r = j * 64 + w * 16 + (l >> 2);      // v-row 0..255
            const int cb = ((l & 3) * 16) ^ (((r >> 1) & 3) << 4);
            const char* src = (const char*)Vb + (size_t)r * (N_ * 2) + itx * 64 + cb;
            gload_lds16(src, (char*)(&Vl[0]) + j * 4096 + w * 1024);
        }
    };

    stage_K(0, 0);      // queue (oldest first): K0, V0, K1  -> 12 outstanding
    stage_V(0);
    stage_K(1, 1);

    f32x4 O[16];
#pragma unroll
    for (int vt = 0; vt < 16; ++vt) O[vt] = (f32x4){0.f, 0.f, 0.f, 0.f};
    f32x4 Ol = (f32x4){0.f, 0.f, 0.f, 0.f};     // P row-sum accumulator (l)
    float mrun[4] = {-1e30f, -1e30f, -1e30f, -1e30f};
    bf16x8 ones;
#pragma unroll
    for (int i = 0; i < 8; ++i) ones[i] = (short)0x3F80;   // bf16 1.0

    ushort* Pw = &Pl[w][0];

    for (int it = 0; it < 72; ++it) {
        const int cur = it & 1;
        // ---- K(it) ready (own quarter), then block-wide
        if (it < 71) { asm volatile("s_waitcnt vmcnt(8)" ::: "memory"); }
        else         { asm volatile("s_waitcnt vmcnt(4)" ::: "memory"); }
        __builtin_amdgcn_s_barrier();
        __builtin_amdgcn_sched_barrier(0);

        const ushort* Kc = &Kl[cur][0];

        // ---- S[16q x 32m] = Q K^T
        f32x4 S0 = (f32x4){0.f, 0.f, 0.f, 0.f};
        f32x4 S1 = (f32x4){0.f, 0.f, 0.f, 0.f};
        __builtin_amdgcn_s_setprio(1);
#pragma unroll
        for (int kc = 0; kc < 8; ++kc) {
            bf16x8 k0 = *reinterpret_cast<const bf16x8*>(Kc + kc * 1024 + rb);
            bf16x8 k1 = *reinterpret_cast<const bf16x8*>(Kc + kc * 1024 + 512 + rb);
            S0 = __builtin_amdgcn_mfma_f32_16x16x32_bf16(qf[kc], k0, S0, 0, 0, 0);
            S1 = __builtin_amdgcn_mfma_f32_16x16x32_bf16(qf[kc], k1, S1, 0, 0, 0);
        }
        __builtin_amdgcn_s_setprio(0);

        // ---- online softmax with defer-max (THR=8)
        float s0[4], s1[4], mx[4];
        bool ok = true;
#pragma unroll
        for (int r = 0; r < 4; ++r) {
            s0[r] = S0[r] * 0.0625f;   // 256^-0.5
            s1[r] = S1[r] * 0.0625f;
            float m2 = fmaxf(s0[r], s1[r]);
#pragma unroll
            for (int off = 1; off < 16; off <<= 1) m2 = fmaxf(m2, __shfl_xor(m2, off, 16));
            mx[r] = m2;
            ok = ok && (m2 <= mrun[r] + 8.f);
        }
        if (!__all(ok)) {
            float corr[4];
#pragma unroll
            for (int r = 0; r < 4; ++r) {
                float mn = fmaxf(mrun[r], mx[r]);
                corr[r] = __expf(mrun[r] - mn);
                mrun[r] = mn;
            }
#pragma unroll
            for (int vt = 0; vt < 16; ++vt) {
                f32x4 o = O[vt];
                o[0] *= corr[0]; o[1] *= corr[1]; o[2] *= corr[2]; o[3] *= corr[3];
                O[vt] = o;
            }
            Ol[0] *= corr[0]; Ol[1] *= corr[1]; Ol[2] *= corr[2]; Ol[3] *= corr[3];
        }
#pragma unroll
        for (int r = 0; r < 4; ++r) {
            const int row = lg * 4 + r;
            const int sw = ((row >> 1) & 3) << 3;
            Pw[row * 32 + (lr ^ sw)] = f2bf(__expf(s0[r] - mrun[r]));
            Pw[row * 32 + ((16 + lr) ^ sw)] = f2bf(__expf(s1[r] - mrun[r]));
        }

        // ---- V(it) ready (own quarter), then block-wide
        if (it < 71) { asm volatile("s_waitcnt vmcnt(4)" ::: "memory"); }
        else         { asm volatile("s_waitcnt vmcnt(0)" ::: "memory"); }
        __builtin_amdgcn_s_barrier();
        __builtin_amdgcn_sched_barrier(0);

        // ---- O += P V^T ; l += P ones^T
        bf16x8 pf = *reinterpret_cast<const bf16x8*>(Pw + rb);
        __builtin_amdgcn_s_setprio(1);
        Ol = __builtin_amdgcn_mfma_f32_16x16x32_bf16(pf, ones, Ol, 0, 0, 0);
#pragma unroll
        for (int vt = 0; vt < 16; ++vt) {
            bf16x8 vf = *reinterpret_cast<const bf16x8*>(Vl + vt * 512 + rb);
            O[vt] = __builtin_amdgcn_mfma_f32_16x16x32_bf16(pf, vf, O[vt], 0, 0, 0);
        }
        __builtin_amdgcn_s_setprio(0);

        __builtin_amdgcn_sched_barrier(0);
        __builtin_amdgcn_s_barrier();        // all waves done reading Vl & Kl[cur]
        if (it < 71) stage_V(it + 1);        // overwrites Vl (safe post-barrier)
        if (it < 70) stage_K(it + 2, cur);   // overwrites Kl[cur]
    }

    // ---- epilogue: normalize by l (= Ol), store ctxT bf16 [b][n][v]
    float il[4];
#pragma unroll
    for (int r = 0; r < 4; ++r) il[r] = 1.0f / Ol[r];
    ushort* Cb = ctxT + ((size_t)b * N_ + q0 + w * 16) * VD;
#pragma unroll
    for (int vt = 0; vt < 16; ++vt) {
#pragma unroll
        for (int j = 0; j < 4; ++j)
            Cb[(size_t)(lg * 4 + j) * VD + vt * 16 + lr] = f2bf(O[vt][j] * il[j]);
    }
}

// --------------- out conv MFMA + folded BN: Z = bf16(bn(Wfb@ctxT^T + bfuse))
__global__ __launch_bounds__(256) void out_mfma(const ushort* __restrict__ Wfb,
                                                const float* __restrict__ bfuse,
                                                const float* __restrict__ rg,
                                                const float* __restrict__ rbta,
                                                const float* __restrict__ rm,
                                                const float* __restrict__ rv,
                                                const ushort* __restrict__ ctxT,
                                                ushort* __restrict__ Z) {
    const int id = blockIdx.x;
    const int b = id & 7;
    const int t = id >> 3;           // 0..287
    const int my = t & 7;            // OD tile
    const int nx = t >> 3;           // 0..35
    const int w = threadIdx.x >> 6, l = threadIdx.x & 63;
    const int lr = l & 15, lg = l >> 4;

    const int m0 = my * 64 + w * 16;
    const ushort* Arow = Wfb + (size_t)(m0 + lr) * VD + lg * 8;
    const ushort* Brow = ctxT + ((size_t)b * N_ + nx * 64 + lr) * VD + lg * 8;

    f32x4 acc[4];
#pragma unroll
    for (int nt = 0; nt < 4; ++nt) acc[nt] = (f32x4){0.f, 0.f, 0.f, 0.f};

#pragma unroll
    for (int kc = 0; kc < 8; ++kc) {
        bf16x8 af = *reinterpret_cast<const bf16x8*>(Arow + kc * 32);
#pragma unroll
        for (int nt = 0; nt < 4; ++nt) {
            bf16x8 bfr = *reinterpret_cast<const bf16x8*>(Brow + (size_t)nt * 16 * VD + kc * 32);
            acc[nt] = __builtin_amdgcn_mfma_f32_16x16x32_bf16(af, bfr, acc[nt], 0, 0, 0);
        }
    }

#pragma unroll
    for (int j = 0; j < 4; ++j) {
        const int o = m0 + lg * 4 + j;
        const float inv = rg[o] * rsqrtf(rv[o] + EPSV);
        const float add = rbta[o] - rm[o] * inv;
        const float bb = bfuse[o];
#pragma unroll
        for (int nt = 0; nt < 4; ++nt) {
            const int n = nx * 64 + nt * 16 + lr;
            Z[((size_t)b * OD + o) * N_ + n] = f2bf((acc[nt][j] + bb) * inv + add);
        }
    }
}

// --------------------------- bilinear upsample (align_corners) + ReLU
// (BN already folded into Z; bilinear commutes with affine since weights sum to 1)
__global__ void upsample_kernel(const ushort* __restrict__ Z,
                                float* __restrict__ out) {
    const int total = B_ * OD * H_ * W_;
    const float s = 47.0f / 95.0f;   // (HP-1)/(H-1), align_corners=True
    for (int idx = blockIdx.x * blockDim.x + threadIdx.x; idx < total;
         idx += gridDim.x * blockDim.x) {
        int x = idx % W_;
        int t = idx / W_;
        int y = t % H_;
        int bo = t / H_;
        float fy = y * s, fx = x * s;
        int y0 = (int)fy, x0 = (int)fx;
        int y1 = min(y0 + 1, HP - 1), x1 = min(x0 + 1, WP - 1);
        float wy = fy - y0, wx = fx - x0;
        const ushort* Zp = Z + (size_t)bo * N_;
        float v00 = bf2f(Zp[y0 * WP + x0]), v01 = bf2f(Zp[y0 * WP + x1]);
        float v10 = bf2f(Zp[y1 * WP + x0]), v11 = bf2f(Zp[y1 * WP + x1]);
        float r0 = v00 + (v01 - v00) * wx;
        float r1 = v10 + (v11 - v10) * wx;
        float v = r0 + (r1 - r0) * wy;
        out[idx] = fmaxf(v, 0.f);
    }
}

extern "C" void kernel_launch(void* const* d_in, const int* in_sizes, int n_in,
                              void* d_out, int out_size, void* d_ws, size_t ws_size,
                              hipStream_t stream) {
    const float* x  = (const float*)d_in[0];
    const float* Wk = (const float*)d_in[1];
    const float* kg = (const float*)d_in[2];
    const float* kb = (const float*)d_in[3];
    const float* km = (const float*)d_in[4];
    const float* kvv= (const float*)d_in[5];
    const float* Wv = (const float*)d_in[6];
    const float* bv = (const float*)d_in[7];
    const float* Ww = (const float*)d_in[8];
    const float* bw = (const float*)d_in[9];
    const float* Wr = (const float*)d_in[10];
    const float* rg = (const float*)d_in[11];
    const float* rb = (const float*)d_in[12];
    const float* rm = (const float*)d_in[13];
    const float* rv = (const float*)d_in[14];

    char* wsb = (char*)d_ws;
    ushort* xpT  = (ushort*)(wsb + BOFF_XPT);
    ushort* qkT  = (ushort*)(wsb + BOFF_QKT);
    ushort* valp = (ushort*)(wsb + BOFF_VAL);
    ushort* ctxT = (ushort*)(wsb + BOFF_CTX);
    ushort* W2   = (ushort*)(wsb + BOFF_W2);
    ushort* Wfb  = (ushort*)(wsb + BOFF_WF);
    float*  bfb  = (float*)(wsb + BOFF_BF);
    ushort* Z    = (ushort*)(wsb + BOFF_XPT);  // overlays xpT (dead after qkv)
    float*  out  = (float*)d_out;

    pool_t_kernel<<<8 * 48 * 8, 192, 0, stream>>>(x, xpT);
    w2_kernel<<<512, 256, 0, stream>>>(Wk, Wv, W2);
    fuse_w_kernel<<<OD, 256, 0, stream>>>(Wr, Ww, Wfb);
    fuse_bias_kernel<<<2, 256, 0, stream>>>(Wr, bw, bfb);
    qkv_mfma<<<2304, 256, 0, stream>>>(W2, xpT, kg, kb, km, kvv, bv, qkT, valp);
    attn_mfma<<<288, 256, 0, stream>>>(qkT, valp, ctxT);
    out_mfma<<<2304, 256, 0, stream>>>(Wfb, bfb, rg, rb, rm, rv, ctxT, Z);
    upsample_kernel<<<4096, 256, 0, stream>>>(Z, out);
}

// Round 6
// 381.100 us; speedup vs baseline: 36.6259x; 1.1289x over previous
//
#include <hip/hip_runtime.h>
#include <math.h>

typedef __attribute__((ext_vector_type(8))) short bf16x8;
typedef __attribute__((ext_vector_type(4))) float f32x4;

namespace {

constexpr int B_ = 8, C_ = 512, H_ = 96, W_ = 96;
constexpr int HP = 48, WP = 48, N_ = HP * WP;   // pooled spatial, N=2304
constexpr int KD = 256, VD = 256, OD = 512;
constexpr int NSPLIT = 4;                        // KV splits
constexpr float EPSV = 1e-5f;

// workspace byte offsets
constexpr size_t BOFF_XPT = 0;                                       // bf16 [B][N][C]
constexpr size_t BOFF_QKT = BOFF_XPT + (size_t)B_ * N_ * C_ * 2;     // bf16 [B][N][KD]
constexpr size_t BOFF_VAL = BOFF_QKT + (size_t)B_ * N_ * KD * 2;     // bf16 [B][VD][N]
constexpr size_t BOFF_CTX = BOFF_VAL + (size_t)B_ * VD * N_ * 2;     // bf16 [B][N][VD]
constexpr size_t BOFF_W2  = BOFF_CTX + (size_t)B_ * N_ * VD * 2;     // bf16 [512][512]
constexpr size_t BOFF_WF  = BOFF_W2  + (size_t)512 * 512 * 2;        // bf16 [OD][VD]
constexpr size_t BOFF_BF  = BOFF_WF  + (size_t)OD * VD * 2;          // fp32 [OD]
constexpr size_t BOFF_PRT = BOFF_BF  + (size_t)OD * 4;               // bf16 [S][B][N][VD]
constexpr size_t BOFF_PM  = BOFF_PRT + (size_t)NSPLIT * B_ * N_ * VD * 2;  // f32 [S][B][N]
constexpr size_t BOFF_PL  = BOFF_PM  + (size_t)NSPLIT * B_ * N_ * 4;       // f32 [S][B][N]
// Z bf16 [B][OD][N] (18.9MB) overlays xpT (18.9MB), dead by then

} // namespace

__device__ __forceinline__ ushort f2bf(float f) {
    union { float f; unsigned u; } x; x.f = f;
    unsigned r = x.u + 0x7FFFu + ((x.u >> 16) & 1u);
    return (ushort)(r >> 16);
}

__device__ __forceinline__ float bf2f(ushort u) {
    union { unsigned u; float f; } x; x.u = ((unsigned)u) << 16;
    return x.f;
}

__device__ __forceinline__ void gload_lds16(const void* g, void* l) {
    __builtin_amdgcn_global_load_lds(
        (const __attribute__((address_space(1))) unsigned int*)g,
        (__attribute__((address_space(3))) unsigned int*)l, 16, 0, 0);
}

// ------------------------ fused maxpool 2x2 + transpose + bf16: x -> xpT[b][n][c]
__global__ __launch_bounds__(192) void pool_t_kernel(const float* __restrict__ x,
                                                     ushort* __restrict__ xpT) {
    __shared__ float ps[64][49];
    const int gid = blockIdx.x;
    const int ct = gid & 7;          // c-tile (64 channels)
    const int tmp = gid >> 3;
    const int oh = tmp % 48;
    const int b  = tmp / 48;
    const int t = threadIdx.x;
    const int ow = t % 48, ci = t / 48;   // ci 0..3

    const int c0 = ct * 64;
#pragma unroll
    for (int pass = 0; pass < 16; ++pass) {
        const int c = pass * 4 + ci;
        const float* px = x + (((size_t)b * C_ + c0 + c) * H_ + 2 * oh) * W_ + 2 * ow;
        float2 a = *reinterpret_cast<const float2*>(px);
        float2 d = *reinterpret_cast<const float2*>(px + W_);
        ps[c][ow] = fmaxf(fmaxf(a.x, a.y), fmaxf(d.x, d.y));
    }
    __syncthreads();
    const int cc = t & 63;
    const int nr0 = t >> 6;          // 0..2
#pragma unroll
    for (int pass = 0; pass < 16; ++pass) {
        const int nr = pass * 3 + nr0;     // 0..47
        xpT[((size_t)b * N_ + oh * 48 + nr) * C_ + c0 + cc] = f2bf(ps[cc][nr]);
    }
}

// ------------------------------------ pack Wk|Wv into bf16 W2 [512][512]
__global__ __launch_bounds__(256) void w2_kernel(const float* __restrict__ Wk,
                                                 const float* __restrict__ Wv,
                                                 ushort* __restrict__ W2) {
    const int m = blockIdx.x;        // 0..511
    const float* src = (m < 256) ? (Wk + (size_t)m * 512) : (Wv + (size_t)(m - 256) * 512);
    const int k = threadIdx.x * 2;
    float2 v = *reinterpret_cast<const float2*>(src + k);
    ushort2 p; p.x = f2bf(v.x); p.y = f2bf(v.y);
    *reinterpret_cast<ushort2*>(&W2[(size_t)m * 512 + k]) = p;
}

// ------------------------------------------------- weight fusion: Wfb = bf16(Wr@Ww)
__global__ __launch_bounds__(256) void fuse_w_kernel(const float* __restrict__ Wr,
                                                     const float* __restrict__ Ww,
                                                     ushort* __restrict__ Wfb) {
    int o = blockIdx.x;    // 0..511
    int v = threadIdx.x;   // 0..255
    float s = 0.f;
    for (int c = 0; c < OD; ++c)
        s = fmaf(Wr[(size_t)o * OD + c], Ww[(size_t)c * VD + v], s);
    Wfb[(size_t)o * VD + v] = f2bf(s);
}

__global__ void fuse_bias_kernel(const float* __restrict__ Wr,
                                 const float* __restrict__ bw,
                                 float* __restrict__ bf) {
    int o = blockIdx.x * blockDim.x + threadIdx.x;
    if (o < OD) {
        float s = 0.f;
        for (int c = 0; c < OD; ++c) s = fmaf(Wr[(size_t)o * OD + c], bw[c], s);
        bf[o] = s;
    }
}

// ------------------------------------- qkv MFMA GEMM: [Wk|Wv] @ xpT^T
__global__ __launch_bounds__(256) void qkv_mfma(
    const ushort* __restrict__ W2, const ushort* __restrict__ xpT,
    const float* __restrict__ kg, const float* __restrict__ kb,
    const float* __restrict__ km, const float* __restrict__ kv,
    const float* __restrict__ bv,
    ushort* __restrict__ qkT, ushort* __restrict__ val) {
    const int id = blockIdx.x;
    const int b = id & 7;
    const int t = id >> 3;           // 0..287
    const int my = t & 7;            // m-tile
    const int nx = t >> 3;           // 0..35
    const int w = threadIdx.x >> 6, l = threadIdx.x & 63;
    const int lr = l & 15, lg = l >> 4;

    const ushort* Xb = xpT + (size_t)b * N_ * C_;
    const int m0 = my * 64 + w * 16;
    const ushort* Arow = W2 + (size_t)(m0 + lr) * 512 + lg * 8;
    const ushort* Brow = Xb + (size_t)(nx * 64 + lr) * 512 + lg * 8;

    f32x4 acc[4];
#pragma unroll
    for (int nt = 0; nt < 4; ++nt) acc[nt] = (f32x4){0.f, 0.f, 0.f, 0.f};

#pragma unroll
    for (int kc = 0; kc < 16; ++kc) {
        bf16x8 af = *reinterpret_cast<const bf16x8*>(Arow + kc * 32);
#pragma unroll
        for (int nt = 0; nt < 4; ++nt) {
            bf16x8 bfr = *reinterpret_cast<const bf16x8*>(Brow + (size_t)nt * 16 * 512 + kc * 32);
            acc[nt] = __builtin_amdgcn_mfma_f32_16x16x32_bf16(af, bfr, acc[nt], 0, 0, 0);
        }
    }

    if (m0 < 256) {
        float inv[4], add[4];
#pragma unroll
        for (int j = 0; j < 4; ++j) {
            int o = m0 + lg * 4 + j;
            inv[j] = kg[o] * rsqrtf(kv[o] + EPSV);
            add[j] = kb[o] - km[o] * inv[j];
        }
#pragma unroll
        for (int nt = 0; nt < 4; ++nt) {
            int n = nx * 64 + nt * 16 + lr;
            ushort4 q4;
            q4.x = f2bf(fmaxf(acc[nt][0] * inv[0] + add[0], 0.f));
            q4.y = f2bf(fmaxf(acc[nt][1] * inv[1] + add[1], 0.f));
            q4.z = f2bf(fmaxf(acc[nt][2] * inv[2] + add[2], 0.f));
            q4.w = f2bf(fmaxf(acc[nt][3] * inv[3] + add[3], 0.f));
            *reinterpret_cast<ushort4*>(&qkT[((size_t)b * N_ + n) * KD + m0 + lg * 4]) = q4;
        }
    } else {
#pragma unroll
        for (int j = 0; j < 4; ++j) {
            int vch = m0 - 256 + lg * 4 + j;
            float bb = bv[vch];
#pragma unroll
            for (int nt = 0; nt < 4; ++nt) {
                int n = nx * 64 + nt * 16 + lr;
                val[((size_t)b * VD + vch) * N_ + n] = f2bf(acc[nt][j] + bb);
            }
        }
    }
}

// ------------------------------------------------------ LDS-staged MFMA flash attention
// 4-way KV split: grid 1152 = 8 b x 36 qt x 4 split; 18 key-tiles per block.
// 53KB LDS -> 3 blocks/CU co-resident (12 waves/CU). Partial O (self-normalized,
// bf16) + (m,l) per row written to workspace; merge_kernel combines 4 splits.
__global__ __launch_bounds__(256, 3) void attn_mfma(const ushort* __restrict__ qkT,
                                                    const ushort* __restrict__ val,
                                                    ushort* __restrict__ part,
                                                    float* __restrict__ pm,
                                                    float* __restrict__ pl) {
    __shared__ ushort Kl[2][8192];   // 2 x 16KB: [kc 8][m 32][32 kd]
    __shared__ ushort Vl[8192];      // 16KB: [v 256][m 32]
    __shared__ ushort Pl[4][512];    // per-wave P [16 q][32 m]

    const int id = blockIdx.x;
    const int b  = id & 7;           // XCD-pinned batch
    const int rest = id >> 3;        // 0..143
    const int s  = rest & 3;         // KV quarter
    const int qt = rest >> 2;        // 0..35
    const int q0 = qt * 64;
    const int t0 = s * 18;           // first key-tile of this split
    const int w  = threadIdx.x >> 6;
    const int l  = threadIdx.x & 63;
    const int lr = l & 15, lg = l >> 4;

    const ushort* Qb = qkT + (size_t)b * N_ * KD;
    const ushort* Vb = val + (size_t)b * VD * N_;

    // shared per-lane swizzled read base (u16 units) for K/V/P 64B-row subtiles
    const int rb = lr * 32 + ((lg * 8) ^ (((lr >> 1) & 3) << 3));

    // resident Q fragments
    bf16x8 qf[8];
    {
        const ushort* qrow = Qb + (size_t)(q0 + w * 16 + lr) * KD + lg * 8;
#pragma unroll
        for (int kc = 0; kc < 8; ++kc)
            qf[kc] = *reinterpret_cast<const bf16x8*>(qrow + kc * 32);
    }
    asm volatile("s_waitcnt vmcnt(0)" ::: "memory");

    auto stage_K = [&](int itx, int buf) {
#pragma unroll
        for (int j = 0; j < 4; ++j) {
            const int prow = j * 64 + w * 16 + (l >> 2);   // kc*32 + m
            const int m = prow & 31;
            const int kc = prow >> 5;
            const int cb = ((l & 3) * 16) ^ (((m >> 1) & 3) << 4);
            const char* src = (const char*)Qb + (size_t)(itx * 32 + m) * (KD * 2) + kc * 64 + cb;
            gload_lds16(src, (char*)(&Kl[buf][0]) + j * 4096 + w * 1024);
        }
    };
    auto stage_V = [&](int itx) {
#pragma unroll
        for (int j = 0; j < 4; ++j) {
            const int r = j * 64 + w * 16 + (l >> 2);      // v-row 0..255
            const int cb = ((l & 3) * 16) ^ (((r >> 1) & 3) << 4);
            const char* src = (const char*)Vb + (size_t)r * (N_ * 2) + itx * 64 + cb;
            gload_lds16(src, (char*)(&Vl[0]) + j * 4096 + w * 1024);
        }
    };

    stage_K(t0, 0);      // queue (oldest first): K0, V0, K1 -> 12 outstanding
    stage_V(t0);
    stage_K(t0 + 1, 1);

    f32x4 O[16];
#pragma unroll
    for (int vt = 0; vt < 16; ++vt) O[vt] = (f32x4){0.f, 0.f, 0.f, 0.f};
    f32x4 Ol = (f32x4){0.f, 0.f, 0.f, 0.f};     // P row-sum accumulator (l)
    float mrun[4] = {-1e30f, -1e30f, -1e30f, -1e30f};
    bf16x8 ones;
#pragma unroll
    for (int i = 0; i < 8; ++i) ones[i] = (short)0x3F80;   // bf16 1.0

    ushort* Pw = &Pl[w][0];

    for (int it = 0; it < 18; ++it) {
        const int cur = it & 1;
        // ---- K(it) ready
        if (it < 17) { asm volatile("s_waitcnt vmcnt(8)" ::: "memory"); }
        else         { asm volatile("s_waitcnt vmcnt(4)" ::: "memory"); }
        __builtin_amdgcn_s_barrier();
        __builtin_amdgcn_sched_barrier(0);

        const ushort* Kc = &Kl[cur][0];

        // ---- S[16q x 32m] = Q K^T
        f32x4 S0 = (f32x4){0.f, 0.f, 0.f, 0.f};
        f32x4 S1 = (f32x4){0.f, 0.f, 0.f, 0.f};
        __builtin_amdgcn_s_setprio(1);
#pragma unroll
        for (int kc = 0; kc < 8; ++kc) {
            bf16x8 k0 = *reinterpret_cast<const bf16x8*>(Kc + kc * 1024 + rb);
            bf16x8 k1 = *reinterpret_cast<const bf16x8*>(Kc + kc * 1024 + 512 + rb);
            S0 = __builtin_amdgcn_mfma_f32_16x16x32_bf16(qf[kc], k0, S0, 0, 0, 0);
            S1 = __builtin_amdgcn_mfma_f32_16x16x32_bf16(qf[kc], k1, S1, 0, 0, 0);
        }
        __builtin_amdgcn_s_setprio(0);

        // ---- online softmax with defer-max (THR=8)
        float s0[4], s1[4], mx[4];
        bool ok = true;
#pragma unroll
        for (int r = 0; r < 4; ++r) {
            s0[r] = S0[r] * 0.0625f;   // 256^-0.5
            s1[r] = S1[r] * 0.0625f;
            float m2 = fmaxf(s0[r], s1[r]);
#pragma unroll
            for (int off = 1; off < 16; off <<= 1) m2 = fmaxf(m2, __shfl_xor(m2, off, 16));
            mx[r] = m2;
            ok = ok && (m2 <= mrun[r] + 8.f);
        }
        if (!__all(ok)) {
            float corr[4];
#pragma unroll
            for (int r = 0; r < 4; ++r) {
                float mn = fmaxf(mrun[r], mx[r]);
                corr[r] = __expf(mrun[r] - mn);
                mrun[r] = mn;
            }
#pragma unroll
            for (int vt = 0; vt < 16; ++vt) {
                f32x4 o = O[vt];
                o[0] *= corr[0]; o[1] *= corr[1]; o[2] *= corr[2]; o[3] *= corr[3];
                O[vt] = o;
            }
            Ol[0] *= corr[0]; Ol[1] *= corr[1]; Ol[2] *= corr[2]; Ol[3] *= corr[3];
        }
#pragma unroll
        for (int r = 0; r < 4; ++r) {
            const int row = lg * 4 + r;
            const int sw = ((row >> 1) & 3) << 3;
            Pw[row * 32 + (lr ^ sw)] = f2bf(__expf(s0[r] - mrun[r]));
            Pw[row * 32 + ((16 + lr) ^ sw)] = f2bf(__expf(s1[r] - mrun[r]));
        }

        // ---- V(it) ready
        if (it < 17) { asm volatile("s_waitcnt vmcnt(4)" ::: "memory"); }
        else         { asm volatile("s_waitcnt vmcnt(0)" ::: "memory"); }
        __builtin_amdgcn_s_barrier();
        __builtin_amdgcn_sched_barrier(0);

        // ---- O += P V^T ; l += P ones^T
        bf16x8 pf = *reinterpret_cast<const bf16x8*>(Pw + rb);
        __builtin_amdgcn_s_setprio(1);
        Ol = __builtin_amdgcn_mfma_f32_16x16x32_bf16(pf, ones, Ol, 0, 0, 0);
#pragma unroll
        for (int vt = 0; vt < 16; ++vt) {
            bf16x8 vf = *reinterpret_cast<const bf16x8*>(Vl + vt * 512 + rb);
            O[vt] = __builtin_amdgcn_mfma_f32_16x16x32_bf16(pf, vf, O[vt], 0, 0, 0);
        }
        __builtin_amdgcn_s_setprio(0);

        __builtin_amdgcn_sched_barrier(0);
        __builtin_amdgcn_s_barrier();               // all waves done reading Vl & Kl[cur]
        if (it < 17) stage_V(t0 + it + 1);
        if (it < 16) stage_K(t0 + it + 2, cur);
    }

    // ---- epilogue: self-normalized partial (bf16) + per-row (m, l)
    float il[4];
#pragma unroll
    for (int r = 0; r < 4; ++r) il[r] = 1.0f / Ol[r];
    ushort* Pp = part + (((size_t)s * B_ + b) * N_ + q0 + w * 16) * VD;
#pragma unroll
    for (int vt = 0; vt < 16; ++vt) {
#pragma unroll
        for (int j = 0; j < 4; ++j)
            Pp[(size_t)(lg * 4 + j) * VD + vt * 16 + lr] = f2bf(O[vt][j] * il[j]);
    }
    if (lr == 0) {
#pragma unroll
        for (int r = 0; r < 4; ++r) {
            const size_t idx = ((size_t)s * B_ + b) * N_ + q0 + w * 16 + lg * 4 + r;
            pm[idx] = mrun[r];
            pl[idx] = Ol[r];
        }
    }
}

// ---------------------- merge 4 KV-split partials -> ctxT bf16 [b][n][v]
// block: 256 thr = 8 rows x 32 lanes (8 v each)
__global__ __launch_bounds__(256) void merge_kernel(const ushort* __restrict__ part,
                                                    const float* __restrict__ pm,
                                                    const float* __restrict__ pl,
                                                    ushort* __restrict__ ctxT) {
    const int row = blockIdx.x * 8 + (threadIdx.x >> 5);   // b*N + n, 0..18431
    const int lane = threadIdx.x & 31;
    const size_t RN = (size_t)B_ * N_;

    float m[NSPLIT], lv[NSPLIT];
#pragma unroll
    for (int si = 0; si < NSPLIT; ++si) {
        m[si]  = pm[si * RN + row];
        lv[si] = pl[si * RN + row];
    }
    float M = fmaxf(fmaxf(m[0], m[1]), fmaxf(m[2], m[3]));
    float wgt[NSPLIT], wsum = 0.f;
#pragma unroll
    for (int si = 0; si < NSPLIT; ++si) {
        wgt[si] = __expf(m[si] - M) * lv[si];
        wsum += wgt[si];
    }
    const float inv = 1.0f / wsum;

    float acc[8] = {};
#pragma unroll
    for (int si = 0; si < NSPLIT; ++si) {
        bf16x8 p = *reinterpret_cast<const bf16x8*>(&part[(si * RN + row) * VD + lane * 8]);
        const float ws = wgt[si];
#pragma unroll
        for (int j = 0; j < 8; ++j) acc[j] = fmaf(ws, bf2f((ushort)p[j]), acc[j]);
    }
    ushort4 o0, o1;
    o0.x = f2bf(acc[0] * inv); o0.y = f2bf(acc[1] * inv);
    o0.z = f2bf(acc[2] * inv); o0.w = f2bf(acc[3] * inv);
    o1.x = f2bf(acc[4] * inv); o1.y = f2bf(acc[5] * inv);
    o1.z = f2bf(acc[6] * inv); o1.w = f2bf(acc[7] * inv);
    ushort* dst = ctxT + (size_t)row * VD + lane * 8;
    *reinterpret_cast<ushort4*>(dst) = o0;
    *reinterpret_cast<ushort4*>(dst + 4) = o1;
}

// --------------- out conv MFMA + folded BN: Z = bf16(bn(Wfb@ctxT^T + bfuse))
__global__ __launch_bounds__(256) void out_mfma(const ushort* __restrict__ Wfb,
                                                const float* __restrict__ bfuse,
                                                const float* __restrict__ rg,
                                                const float* __restrict__ rbta,
                                                const float* __restrict__ rm,
                                                const float* __restrict__ rv,
                                                const ushort* __restrict__ ctxT,
                                                ushort* __restrict__ Z) {
    const int id = blockIdx.x;
    const int b = id & 7;
    const int t = id >> 3;           // 0..287
    const int my = t & 7;            // OD tile
    const int nx = t >> 3;           // 0..35
    const int w = threadIdx.x >> 6, l = threadIdx.x & 63;
    const int lr = l & 15, lg = l >> 4;

    const int m0 = my * 64 + w * 16;
    const ushort* Arow = Wfb + (size_t)(m0 + lr) * VD + lg * 8;
    const ushort* Brow = ctxT + ((size_t)b * N_ + nx * 64 + lr) * VD + lg * 8;

    f32x4 acc[4];
#pragma unroll
    for (int nt = 0; nt < 4; ++nt) acc[nt] = (f32x4){0.f, 0.f, 0.f, 0.f};

#pragma unroll
    for (int kc = 0; kc < 8; ++kc) {
        bf16x8 af = *reinterpret_cast<const bf16x8*>(Arow + kc * 32);
#pragma unroll
        for (int nt = 0; nt < 4; ++nt) {
            bf16x8 bfr = *reinterpret_cast<const bf16x8*>(Brow + (size_t)nt * 16 * VD + kc * 32);
            acc[nt] = __builtin_amdgcn_mfma_f32_16x16x32_bf16(af, bfr, acc[nt], 0, 0, 0);
        }
    }

#pragma unroll
    for (int j = 0; j < 4; ++j) {
        const int o = m0 + lg * 4 + j;
        const float inv = rg[o] * rsqrtf(rv[o] + EPSV);
        const float add = rbta[o] - rm[o] * inv;
        const float bb = bfuse[o];
#pragma unroll
        for (int nt = 0; nt < 4; ++nt) {
            const int n = nx * 64 + nt * 16 + lr;
            Z[((size_t)b * OD + o) * N_ + n] = f2bf((acc[nt][j] + bb) * inv + add);
        }
    }
}

// --------------------------- bilinear upsample (align_corners) + ReLU
__global__ void upsample_kernel(const ushort* __restrict__ Z,
                                float* __restrict__ out) {
    const int total = B_ * OD * H_ * W_;
    const float s = 47.0f / 95.0f;   // (HP-1)/(H-1), align_corners=True
    for (int idx = blockIdx.x * blockDim.x + threadIdx.x; idx < total;
         idx += gridDim.x * blockDim.x) {
        int x = idx % W_;
        int t = idx / W_;
        int y = t % H_;
        int bo = t / H_;
        float fy = y * s, fx = x * s;
        int y0 = (int)fy, x0 = (int)fx;
        int y1 = min(y0 + 1, HP - 1), x1 = min(x0 + 1, WP - 1);
        float wy = fy - y0, wx = fx - x0;
        const ushort* Zp = Z + (size_t)bo * N_;
        float v00 = bf2f(Zp[y0 * WP + x0]), v01 = bf2f(Zp[y0 * WP + x1]);
        float v10 = bf2f(Zp[y1 * WP + x0]), v11 = bf2f(Zp[y1 * WP + x1]);
        float r0 = v00 + (v01 - v00) * wx;
        float r1 = v10 + (v11 - v10) * wx;
        float v = r0 + (r1 - r0) * wy;
        out[idx] = fmaxf(v, 0.f);
    }
}

extern "C" void kernel_launch(void* const* d_in, const int* in_sizes, int n_in,
                              void* d_out, int out_size, void* d_ws, size_t ws_size,
                              hipStream_t stream) {
    const float* x  = (const float*)d_in[0];
    const float* Wk = (const float*)d_in[1];
    const float* kg = (const float*)d_in[2];
    const float* kb = (const float*)d_in[3];
    const float* km = (const float*)d_in[4];
    const float* kvv= (const float*)d_in[5];
    const float* Wv = (const float*)d_in[6];
    const float* bv = (const float*)d_in[7];
    const float* Ww = (const float*)d_in[8];
    const float* bw = (const float*)d_in[9];
    const float* Wr = (const float*)d_in[10];
    const float* rg = (const float*)d_in[11];
    const float* rb = (const float*)d_in[12];
    const float* rm = (const float*)d_in[13];
    const float* rv = (const float*)d_in[14];

    char* wsb = (char*)d_ws;
    ushort* xpT  = (ushort*)(wsb + BOFF_XPT);
    ushort* qkT  = (ushort*)(wsb + BOFF_QKT);
    ushort* valp = (ushort*)(wsb + BOFF_VAL);
    ushort* ctxT = (ushort*)(wsb + BOFF_CTX);
    ushort* W2   = (ushort*)(wsb + BOFF_W2);
    ushort* Wfb  = (ushort*)(wsb + BOFF_WF);
    float*  bfb  = (float*)(wsb + BOFF_BF);
    ushort* part = (ushort*)(wsb + BOFF_PRT);
    float*  pm   = (float*)(wsb + BOFF_PM);
    float*  pl   = (float*)(wsb + BOFF_PL);
    ushort* Z    = (ushort*)(wsb + BOFF_XPT);  // overlays xpT (dead after qkv)
    float*  out  = (float*)d_out;

    pool_t_kernel<<<8 * 48 * 8, 192, 0, stream>>>(x, xpT);
    w2_kernel<<<512, 256, 0, stream>>>(Wk, Wv, W2);
    fuse_w_kernel<<<OD, 256, 0, stream>>>(Wr, Ww, Wfb);
    fuse_bias_kernel<<<2, 256, 0, stream>>>(Wr, bw, bfb);
    qkv_mfma<<<2304, 256, 0, stream>>>(W2, xpT, kg, kb, km, kvv, bv, qkT, valp);
    attn_mfma<<<1152, 256, 0, stream>>>(qkT, valp, part, pm, pl);
    merge_kernel<<<(B_ * N_) / 8, 256, 0, stream>>>(part, pm, pl, ctxT);
    out_mfma<<<2304, 256, 0, stream>>>(Wfb, bfb, rg, rb, rm, rv, ctxT, Z);
    upsample_kernel<<<4096, 256, 0, stream>>>(Z, out);
}

// Round 7
// 293.835 us; speedup vs baseline: 47.5033x; 1.2970x over previous
//
#include <hip/hip_runtime.h>
#include <math.h>

typedef __attribute__((ext_vector_type(8))) short bf16x8;
typedef __attribute__((ext_vector_type(4))) float f32x4;

namespace {

constexpr int B_ = 8, C_ = 512, H_ = 96, W_ = 96;
constexpr int HP = 48, WP = 48, N_ = HP * WP;   // pooled spatial, N=2304
constexpr int KD = 256, VD = 256, OD = 512;
constexpr int NSPLIT = 4;                        // KV splits
constexpr float EPSV = 1e-5f;
constexpr float LOG2E = 1.44269504088896f;

// workspace byte offsets
constexpr size_t BOFF_XPT = 0;                                       // bf16 [B][N][C]
constexpr size_t BOFF_QKT = BOFF_XPT + (size_t)B_ * N_ * C_ * 2;     // bf16 [B][N][KD]
constexpr size_t BOFF_VAL = BOFF_QKT + (size_t)B_ * N_ * KD * 2;     // bf16 [B][VD][N]
constexpr size_t BOFF_CTX = BOFF_VAL + (size_t)B_ * VD * N_ * 2;     // bf16 [B][N][VD]
constexpr size_t BOFF_W2  = BOFF_CTX + (size_t)B_ * N_ * VD * 2;     // bf16 [512][512]
constexpr size_t BOFF_WF  = BOFF_W2  + (size_t)512 * 512 * 2;        // bf16 [OD][VD]
constexpr size_t BOFF_BF  = BOFF_WF  + (size_t)OD * VD * 2;          // fp32 [OD]
constexpr size_t BOFF_PRT = BOFF_BF  + (size_t)OD * 4;               // bf16 [S][B][N][VD]
constexpr size_t BOFF_PM  = BOFF_PRT + (size_t)NSPLIT * B_ * N_ * VD * 2;  // f32 [S][B][N]
constexpr size_t BOFF_PL  = BOFF_PM  + (size_t)NSPLIT * B_ * N_ * 4;       // f32 [S][B][N]
// Z bf16 [B][OD][N] (18.9MB) overlays xpT (18.9MB), dead by then

} // namespace

__device__ __forceinline__ ushort f2bf(float f) {
    union { float f; unsigned u; } x; x.f = f;
    unsigned r = x.u + 0x7FFFu + ((x.u >> 16) & 1u);
    return (ushort)(r >> 16);
}

__device__ __forceinline__ float bf2f(ushort u) {
    union { unsigned u; float f; } x; x.u = ((unsigned)u) << 16;
    return x.f;
}

__device__ __forceinline__ void gload_lds16(const void* g, void* l) {
    __builtin_amdgcn_global_load_lds(
        (const __attribute__((address_space(1))) unsigned int*)g,
        (__attribute__((address_space(3))) unsigned int*)l, 16, 0, 0);
}

// ------------------------ fused maxpool 2x2 + transpose + bf16: x -> xpT[b][n][c]
__global__ __launch_bounds__(192) void pool_t_kernel(const float* __restrict__ x,
                                                     ushort* __restrict__ xpT) {
    __shared__ float ps[64][49];
    const int gid = blockIdx.x;
    const int ct = gid & 7;          // c-tile (64 channels)
    const int tmp = gid >> 3;
    const int oh = tmp % 48;
    const int b  = tmp / 48;
    const int t = threadIdx.x;
    const int ow = t % 48, ci = t / 48;   // ci 0..3

    const int c0 = ct * 64;
#pragma unroll
    for (int pass = 0; pass < 16; ++pass) {
        const int c = pass * 4 + ci;
        const float* px = x + (((size_t)b * C_ + c0 + c) * H_ + 2 * oh) * W_ + 2 * ow;
        float2 a = *reinterpret_cast<const float2*>(px);
        float2 d = *reinterpret_cast<const float2*>(px + W_);
        ps[c][ow] = fmaxf(fmaxf(a.x, a.y), fmaxf(d.x, d.y));
    }
    __syncthreads();
    const int cc2 = (t & 31) * 2;
    const int nr0 = t >> 5;          // 0..5
#pragma unroll
    for (int pass = 0; pass < 8; ++pass) {
        const int nr = pass * 6 + nr0;     // 0..47
        ushort2 p2;
        p2.x = f2bf(ps[cc2][nr]);
        p2.y = f2bf(ps[cc2 + 1][nr]);
        *reinterpret_cast<ushort2*>(&xpT[((size_t)b * N_ + oh * 48 + nr) * C_ + c0 + cc2]) = p2;
    }
}

// ---------------- prep: pack W2 bf16 | fuse Wfb = bf16(Wr@Ww) | bfuse = Wr@bw
__global__ __launch_bounds__(256) void prep_kernel(const float* __restrict__ Wk,
                                                   const float* __restrict__ Wv,
                                                   const float* __restrict__ Wr,
                                                   const float* __restrict__ Ww,
                                                   const float* __restrict__ bw,
                                                   ushort* __restrict__ W2,
                                                   ushort* __restrict__ Wfb,
                                                   float* __restrict__ bfb) {
    const int blk = blockIdx.x;
    if (blk < 512) {
        const int m = blk;
        const float* src = (m < 256) ? (Wk + (size_t)m * 512) : (Wv + (size_t)(m - 256) * 512);
        const int k = threadIdx.x * 2;
        float2 v = *reinterpret_cast<const float2*>(src + k);
        ushort2 p; p.x = f2bf(v.x); p.y = f2bf(v.y);
        *reinterpret_cast<ushort2*>(&W2[(size_t)m * 512 + k]) = p;
    } else if (blk < 1024) {
        const int o = blk - 512;
        const int v = threadIdx.x;
        float s = 0.f;
        for (int c = 0; c < OD; ++c)
            s = fmaf(Wr[(size_t)o * OD + c], Ww[(size_t)c * VD + v], s);
        Wfb[(size_t)o * VD + v] = f2bf(s);
    } else {
        const int o = (blk - 1024) * 256 + threadIdx.x;
        float s = 0.f;
        for (int c = 0; c < OD; ++c) s = fmaf(Wr[(size_t)o * OD + c], bw[c], s);
        bfb[o] = s;
    }
}

// ------------------------------------- qkv MFMA GEMM (LDS-staged, 2-phase):
// [Wk|Wv](512x512) @ xpT^T -> qkT bf16 [b][n][kd] (BN+ReLU) / val bf16 [b][v][n]
__global__ __launch_bounds__(256) void qkv_mfma(
    const ushort* __restrict__ W2, const ushort* __restrict__ xpT,
    const float* __restrict__ kg, const float* __restrict__ kb,
    const float* __restrict__ km, const float* __restrict__ kv,
    const float* __restrict__ bv,
    ushort* __restrict__ qkT, ushort* __restrict__ val) {
    __shared__ ushort Al[2][4096];   // 8KB tile: [kc 2][64 m][32 k], 64B-row swizzled
    __shared__ ushort Bl[2][4096];

    const int id = blockIdx.x;
    const int b = id & 7;
    const int t = id >> 3;           // 0..287
    const int my = t & 7;            // m-tile
    const int nx = t >> 3;           // 0..35
    const int w = threadIdx.x >> 6, l = threadIdx.x & 63;
    const int lr = l & 15, lg = l >> 4;
    const int rbq = (lg * 8) ^ (((lr >> 1) & 3) << 3);

    const ushort* srcA = W2 + (size_t)(my * 64) * 512;              // ld 512
    const ushort* srcB = xpT + ((size_t)b * N_ + nx * 64) * 512;    // ld 512

    auto stage64 = [&](const ushort* src, int koff, char* lbase) {
#pragma unroll
        for (int j = 0; j < 2; ++j) {
            const int prow = j * 64 + w * 16 + (l >> 2);   // 0..127
            const int row = prow & 63;
            const int kc = prow >> 6;
            const int cb = ((l & 3) * 16) ^ (((row >> 1) & 3) << 4);
            const char* s = (const char*)(src + (size_t)row * 512 + koff) + kc * 64 + cb;
            gload_lds16(s, lbase + j * 4096 + w * 1024);
        }
    };

    stage64(srcA, 0, (char*)&Al[0][0]);
    stage64(srcB, 0, (char*)&Bl[0][0]);
    stage64(srcA, 64, (char*)&Al[1][0]);
    stage64(srcB, 64, (char*)&Bl[1][0]);

    f32x4 acc[4];
#pragma unroll
    for (int nt = 0; nt < 4; ++nt) acc[nt] = (f32x4){0.f, 0.f, 0.f, 0.f};

    for (int ks = 0; ks < 8; ++ks) {
        if (ks < 7) { asm volatile("s_waitcnt vmcnt(4)" ::: "memory"); }
        else        { asm volatile("s_waitcnt vmcnt(0)" ::: "memory"); }
        __builtin_amdgcn_s_barrier();
        __builtin_amdgcn_sched_barrier(0);
        const ushort* Ab = &Al[ks & 1][0];
        const ushort* Bb = &Bl[ks & 1][0];
        __builtin_amdgcn_s_setprio(1);
#pragma unroll
        for (int kc = 0; kc < 2; ++kc) {
            bf16x8 af = *reinterpret_cast<const bf16x8*>(Ab + kc * 2048 + (w * 16 + lr) * 32 + rbq);
#pragma unroll
            for (int nt = 0; nt < 4; ++nt) {
                bf16x8 bfr = *reinterpret_cast<const bf16x8*>(Bb + kc * 2048 + (nt * 16 + lr) * 32 + rbq);
                acc[nt] = __builtin_amdgcn_mfma_f32_16x16x32_bf16(af, bfr, acc[nt], 0, 0, 0);
            }
        }
        __builtin_amdgcn_s_setprio(0);
        __builtin_amdgcn_sched_barrier(0);
        __builtin_amdgcn_s_barrier();
        if (ks < 6) {
            stage64(srcA, (ks + 2) * 64, (char*)&Al[ks & 1][0]);
            stage64(srcB, (ks + 2) * 64, (char*)&Bl[ks & 1][0]);
        }
    }

    const int m0 = my * 64 + w * 16;
    if (m0 < 256) {
        float inv[4], add[4];
#pragma unroll
        for (int j = 0; j < 4; ++j) {
            int o = m0 + lg * 4 + j;
            inv[j] = kg[o] * rsqrtf(kv[o] + EPSV);
            add[j] = kb[o] - km[o] * inv[j];
        }
#pragma unroll
        for (int nt = 0; nt < 4; ++nt) {
            int n = nx * 64 + nt * 16 + lr;
            ushort4 q4;
            q4.x = f2bf(fmaxf(acc[nt][0] * inv[0] + add[0], 0.f));
            q4.y = f2bf(fmaxf(acc[nt][1] * inv[1] + add[1], 0.f));
            q4.z = f2bf(fmaxf(acc[nt][2] * inv[2] + add[2], 0.f));
            q4.w = f2bf(fmaxf(acc[nt][3] * inv[3] + add[3], 0.f));
            *reinterpret_cast<ushort4*>(&qkT[((size_t)b * N_ + n) * KD + m0 + lg * 4]) = q4;
        }
    } else {
#pragma unroll
        for (int j = 0; j < 4; ++j) {
            int vch = m0 - 256 + lg * 4 + j;
            float bb = bv[vch];
#pragma unroll
            for (int nt = 0; nt < 4; ++nt) {
                int n = nx * 64 + nt * 16 + lr;
                val[((size_t)b * VD + vch) * N_ + n] = f2bf(acc[nt][j] + bb);
            }
        }
    }
}

// ------------------------------------------------------ LDS-staged MFMA flash attention
// 4-way KV split; K AND V double-buffered -> 2 barriers/iter, deep load slack.
// 68KB LDS -> 2 blocks/CU. Softmax in exp2 domain. Partials + (m,l) to workspace.
__global__ __launch_bounds__(256, 2) void attn_mfma(const ushort* __restrict__ qkT,
                                                    const ushort* __restrict__ val,
                                                    ushort* __restrict__ part,
                                                    float* __restrict__ pm,
                                                    float* __restrict__ pl) {
    __shared__ ushort Kl[2][8192];   // 2 x 16KB: [kc 8][m 32][32 kd]
    __shared__ ushort Vl[2][8192];   // 2 x 16KB: [v 256][m 32]
    __shared__ ushort Pl[4][512];    // per-wave P [16 q][32 m]

    const int id = blockIdx.x;
    const int b  = id & 7;           // XCD-pinned batch
    const int rest = id >> 3;        // 0..143
    const int s  = rest & 3;         // KV quarter
    const int qt = rest >> 2;        // 0..35
    const int q0 = qt * 64;
    const int t0 = s * 18;           // first key-tile of this split
    const int w  = threadIdx.x >> 6;
    const int l  = threadIdx.x & 63;
    const int lr = l & 15, lg = l >> 4;

    const ushort* Qb = qkT + (size_t)b * N_ * KD;
    const ushort* Vb = val + (size_t)b * VD * N_;

    const int rb = lr * 32 + ((lg * 8) ^ (((lr >> 1) & 3) << 3));

    // resident Q fragments
    bf16x8 qf[8];
    {
        const ushort* qrow = Qb + (size_t)(q0 + w * 16 + lr) * KD + lg * 8;
#pragma unroll
        for (int kc = 0; kc < 8; ++kc)
            qf[kc] = *reinterpret_cast<const bf16x8*>(qrow + kc * 32);
    }
    asm volatile("s_waitcnt vmcnt(0)" ::: "memory");

    auto stage_K = [&](int itx, int buf) {
#pragma unroll
        for (int j = 0; j < 4; ++j) {
            const int prow = j * 64 + w * 16 + (l >> 2);   // kc*32 + m
            const int m = prow & 31;
            const int kc = prow >> 5;
            const int cb = ((l & 3) * 16) ^ (((m >> 1) & 3) << 4);
            const char* src = (const char*)Qb + (size_t)(itx * 32 + m) * (KD * 2) + kc * 64 + cb;
            gload_lds16(src, (char*)(&Kl[buf][0]) + j * 4096 + w * 1024);
        }
    };
    auto stage_V = [&](int itx, int buf) {
#pragma unroll
        for (int j = 0; j < 4; ++j) {
            const int r = j * 64 + w * 16 + (l >> 2);      // v-row 0..255
            const int cb = ((l & 3) * 16) ^ (((r >> 1) & 3) << 4);
            const char* src = (const char*)Vb + (size_t)r * (N_ * 2) + itx * 64 + cb;
            gload_lds16(src, (char*)(&Vl[buf][0]) + j * 4096 + w * 1024);
        }
    };

    stage_K(t0, 0);      // queue (oldest first): K0, V0, K1 -> 12 outstanding
    stage_V(t0, 0);
    stage_K(t0 + 1, 1);

    f32x4 O[16];
#pragma unroll
    for (int vt = 0; vt < 16; ++vt) O[vt] = (f32x4){0.f, 0.f, 0.f, 0.f};
    f32x4 Ol = (f32x4){0.f, 0.f, 0.f, 0.f};     // P row-sum accumulator (l)
    float mrun[4] = {-1e30f, -1e30f, -1e30f, -1e30f};   // log2 domain
    bf16x8 ones;
#pragma unroll
    for (int i = 0; i < 8; ++i) ones[i] = (short)0x3F80;   // bf16 1.0

    const float SC = 0.0625f * LOG2E;
    ushort* Pw = &Pl[w][0];

    for (int it = 0; it < 18; ++it) {
        const int cur = it & 1;
        // ---- K(it) ready: outstanding [K(it),V(it),K(it+1)]=12 -> 8
        if (it < 17) { asm volatile("s_waitcnt vmcnt(8)" ::: "memory"); }
        else         { asm volatile("s_waitcnt vmcnt(4)" ::: "memory"); }
        __builtin_amdgcn_s_barrier();
        __builtin_amdgcn_sched_barrier(0);
        if (it < 17) stage_V(t0 + it + 1, cur ^ 1);   // buf last read in PV(it-1)

        const ushort* Kc = &Kl[cur][0];

        // ---- S[16q x 32m] = Q K^T
        f32x4 S0 = (f32x4){0.f, 0.f, 0.f, 0.f};
        f32x4 S1 = (f32x4){0.f, 0.f, 0.f, 0.f};
        __builtin_amdgcn_s_setprio(1);
#pragma unroll
        for (int kc = 0; kc < 8; ++kc) {
            bf16x8 k0 = *reinterpret_cast<const bf16x8*>(Kc + kc * 1024 + rb);
            bf16x8 k1 = *reinterpret_cast<const bf16x8*>(Kc + kc * 1024 + 512 + rb);
            S0 = __builtin_amdgcn_mfma_f32_16x16x32_bf16(qf[kc], k0, S0, 0, 0, 0);
            S1 = __builtin_amdgcn_mfma_f32_16x16x32_bf16(qf[kc], k1, S1, 0, 0, 0);
        }
        __builtin_amdgcn_s_setprio(0);

        // ---- online softmax, exp2 domain, defer-max (THR ~ 8 nats)
        float s0[4], s1[4], mx[4];
        bool ok = true;
#pragma unroll
        for (int r = 0; r < 4; ++r) {
            s0[r] = S0[r] * SC;
            s1[r] = S1[r] * SC;
            float m2 = fmaxf(s0[r], s1[r]);
#pragma unroll
            for (int off = 1; off < 16; off <<= 1) m2 = fmaxf(m2, __shfl_xor(m2, off, 16));
            mx[r] = m2;
            ok = ok && (m2 <= mrun[r] + 11.5f);
        }
        if (!__all(ok)) {
            float corr[4];
#pragma unroll
            for (int r = 0; r < 4; ++r) {
                float mn = fmaxf(mrun[r], mx[r]);
                corr[r] = exp2f(mrun[r] - mn);
                mrun[r] = mn;
            }
#pragma unroll
            for (int vt = 0; vt < 16; ++vt) {
                f32x4 o = O[vt];
                o[0] *= corr[0]; o[1] *= corr[1]; o[2] *= corr[2]; o[3] *= corr[3];
                O[vt] = o;
            }
            Ol[0] *= corr[0]; Ol[1] *= corr[1]; Ol[2] *= corr[2]; Ol[3] *= corr[3];
        }
#pragma unroll
        for (int r = 0; r < 4; ++r) {
            const int row = lg * 4 + r;
            const int sw = ((row >> 1) & 3) << 3;
            Pw[row * 32 + (lr ^ sw)] = f2bf(exp2f(s0[r] - mrun[r]));
            Pw[row * 32 + ((16 + lr) ^ sw)] = f2bf(exp2f(s1[r] - mrun[r]));
        }

        // ---- V(it) ready: outstanding [V(it),K(it+1),V(it+1)]=12 -> 8
        if (it < 17) { asm volatile("s_waitcnt vmcnt(8)" ::: "memory"); }
        else         { asm volatile("s_waitcnt vmcnt(0)" ::: "memory"); }
        __builtin_amdgcn_s_barrier();
        __builtin_amdgcn_sched_barrier(0);
        if (it < 16) stage_K(t0 + it + 2, cur);       // Kl[cur] free after QK(it)

        // ---- O += P V^T ; l += P ones^T
        bf16x8 pf = *reinterpret_cast<const bf16x8*>(Pw + rb);
        const ushort* Vc = &Vl[cur][0];
        __builtin_amdgcn_s_setprio(1);
        Ol = __builtin_amdgcn_mfma_f32_16x16x32_bf16(pf, ones, Ol, 0, 0, 0);
#pragma unroll
        for (int vt = 0; vt < 16; ++vt) {
            bf16x8 vf = *reinterpret_cast<const bf16x8*>(Vc + vt * 512 + rb);
            O[vt] = __builtin_amdgcn_mfma_f32_16x16x32_bf16(pf, vf, O[vt], 0, 0, 0);
        }
        __builtin_amdgcn_s_setprio(0);
    }

    // ---- epilogue: self-normalized partial (bf16) + per-row (m, l)
    float il[4];
#pragma unroll
    for (int r = 0; r < 4; ++r) il[r] = 1.0f / Ol[r];
    ushort* Pp = part + (((size_t)s * B_ + b) * N_ + q0 + w * 16) * VD;
#pragma unroll
    for (int vt = 0; vt < 16; ++vt) {
#pragma unroll
        for (int j = 0; j < 4; ++j)
            Pp[(size_t)(lg * 4 + j) * VD + vt * 16 + lr] = f2bf(O[vt][j] * il[j]);
    }
    if (lr == 0) {
#pragma unroll
        for (int r = 0; r < 4; ++r) {
            const size_t idx = ((size_t)s * B_ + b) * N_ + q0 + w * 16 + lg * 4 + r;
            pm[idx] = mrun[r];
            pl[idx] = Ol[r];
        }
    }
}

// ---------------------- merge 4 KV-split partials -> ctxT bf16 [b][n][v]
__global__ __launch_bounds__(256) void merge_kernel(const ushort* __restrict__ part,
                                                    const float* __restrict__ pm,
                                                    const float* __restrict__ pl,
                                                    ushort* __restrict__ ctxT) {
    const int row = blockIdx.x * 8 + (threadIdx.x >> 5);   // b*N + n
    const int lane = threadIdx.x & 31;
    const size_t RN = (size_t)B_ * N_;

    float m[NSPLIT], lv[NSPLIT];
#pragma unroll
    for (int si = 0; si < NSPLIT; ++si) {
        m[si]  = pm[si * RN + row];
        lv[si] = pl[si * RN + row];
    }
    float M = fmaxf(fmaxf(m[0], m[1]), fmaxf(m[2], m[3]));
    float wgt[NSPLIT], wsum = 0.f;
#pragma unroll
    for (int si = 0; si < NSPLIT; ++si) {
        wgt[si] = exp2f(m[si] - M) * lv[si];   // log2-domain maxes
        wsum += wgt[si];
    }
    const float inv = 1.0f / wsum;

    float acc[8] = {};
#pragma unroll
    for (int si = 0; si < NSPLIT; ++si) {
        bf16x8 p = *reinterpret_cast<const bf16x8*>(&part[(si * RN + row) * VD + lane * 8]);
        const float ws = wgt[si];
#pragma unroll
        for (int j = 0; j < 8; ++j) acc[j] = fmaf(ws, bf2f((ushort)p[j]), acc[j]);
    }
    ushort4 o0, o1;
    o0.x = f2bf(acc[0] * inv); o0.y = f2bf(acc[1] * inv);
    o0.z = f2bf(acc[2] * inv); o0.w = f2bf(acc[3] * inv);
    o1.x = f2bf(acc[4] * inv); o1.y = f2bf(acc[5] * inv);
    o1.z = f2bf(acc[6] * inv); o1.w = f2bf(acc[7] * inv);
    ushort* dst = ctxT + (size_t)row * VD + lane * 8;
    *reinterpret_cast<ushort4*>(dst) = o0;
    *reinterpret_cast<ushort4*>(dst + 4) = o1;
}

// ------------- out conv MFMA (LDS-staged) + folded BN: Z = bf16(bn(Wfb@ctxT^T + bfuse))
__global__ __launch_bounds__(256) void out_mfma(const ushort* __restrict__ Wfb,
                                                const float* __restrict__ bfuse,
                                                const float* __restrict__ rg,
                                                const float* __restrict__ rbta,
                                                const float* __restrict__ rm,
                                                const float* __restrict__ rv,
                                                const ushort* __restrict__ ctxT,
                                                ushort* __restrict__ Z) {
    __shared__ ushort Al[2][4096];
    __shared__ ushort Bl[2][4096];

    const int id = blockIdx.x;
    const int b = id & 7;
    const int t = id >> 3;           // 0..287
    const int my = t & 7;            // OD tile
    const int nx = t >> 3;           // 0..35
    const int w = threadIdx.x >> 6, l = threadIdx.x & 63;
    const int lr = l & 15, lg = l >> 4;
    const int rbq = (lg * 8) ^ (((lr >> 1) & 3) << 3);

    const ushort* srcA = Wfb + (size_t)(my * 64) * VD;               // ld 256
    const ushort* srcB = ctxT + ((size_t)b * N_ + nx * 64) * VD;     // ld 256

    auto stage64 = [&](const ushort* src, int koff, char* lbase) {
#pragma unroll
        for (int j = 0; j < 2; ++j) {
            const int prow = j * 64 + w * 16 + (l >> 2);
            const int row = prow & 63;
            const int kc = prow >> 6;
            const int cb = ((l & 3) * 16) ^ (((row >> 1) & 3) << 4);
            const char* s = (const char*)(src + (size_t)row * VD + koff) + kc * 64 + cb;
            gload_lds16(s, lbase + j * 4096 + w * 1024);
        }
    };

    stage64(srcA, 0, (char*)&Al[0][0]);
    stage64(srcB, 0, (char*)&Bl[0][0]);
    stage64(srcA, 64, (char*)&Al[1][0]);
    stage64(srcB, 64, (char*)&Bl[1][0]);

    f32x4 acc[4];
#pragma unroll
    for (int nt = 0; nt < 4; ++nt) acc[nt] = (f32x4){0.f, 0.f, 0.f, 0.f};

    for (int ks = 0; ks < 4; ++ks) {
        if (ks < 3) { asm volatile("s_waitcnt vmcnt(4)" ::: "memory"); }
        else        { asm volatile("s_waitcnt vmcnt(0)" ::: "memory"); }
        __builtin_amdgcn_s_barrier();
        __builtin_amdgcn_sched_barrier(0);
        const ushort* Ab = &Al[ks & 1][0];
        const ushort* Bb = &Bl[ks & 1][0];
        __builtin_amdgcn_s_setprio(1);
#pragma unroll
        for (int kc = 0; kc < 2; ++kc) {
            bf16x8 af = *reinterpret_cast<const bf16x8*>(Ab + kc * 2048 + (w * 16 + lr) * 32 + rbq);
#pragma unroll
            for (int nt = 0; nt < 4; ++nt) {
                bf16x8 bfr = *reinterpret_cast<const bf16x8*>(Bb + kc * 2048 + (nt * 16 + lr) * 32 + rbq);
                acc[nt] = __builtin_amdgcn_mfma_f32_16x16x32_bf16(af, bfr, acc[nt], 0, 0, 0);
            }
        }
        __builtin_amdgcn_s_setprio(0);
        __builtin_amdgcn_sched_barrier(0);
        __builtin_amdgcn_s_barrier();
        if (ks < 2) {
            stage64(srcA, (ks + 2) * 64, (char*)&Al[ks & 1][0]);
            stage64(srcB, (ks + 2) * 64, (char*)&Bl[ks & 1][0]);
        }
    }

    const int m0 = my * 64 + w * 16;
#pragma unroll
    for (int j = 0; j < 4; ++j) {
        const int o = m0 + lg * 4 + j;
        const float inv = rg[o] * rsqrtf(rv[o] + EPSV);
        const float add = rbta[o] - rm[o] * inv;
        const float bb = bfuse[o];
#pragma unroll
        for (int nt = 0; nt < 4; ++nt) {
            const int n = nx * 64 + nt * 16 + lr;
            Z[((size_t)b * OD + o) * N_ + n] = f2bf((acc[nt][j] + bb) * inv + add);
        }
    }
}

// --------------------------- bilinear upsample (align_corners) + ReLU, x4 vectorized
__global__ void upsample_kernel(const ushort* __restrict__ Z,
                                float* __restrict__ out) {
    const int total = B_ * OD * H_ * (W_ / 4);
    const float s = 47.0f / 95.0f;
    for (int idx = blockIdx.x * blockDim.x + threadIdx.x; idx < total;
         idx += gridDim.x * blockDim.x) {
        const int xq = idx % 24;
        const int t = idx / 24;
        const int y = t % H_;
        const int bo = t / H_;
        const float fy = y * s;
        const int y0 = (int)fy;
        const int y1 = min(y0 + 1, HP - 1);
        const float wy = fy - y0;
        const ushort* Zp = Z + (size_t)bo * N_;
        const ushort* r0 = Zp + y0 * WP;
        const ushort* r1 = Zp + y1 * WP;
        float4 o4;
        float* po = &o4.x;
#pragma unroll
        for (int j = 0; j < 4; ++j) {
            const int x = xq * 4 + j;
            const float fx = x * s;
            const int x0 = (int)fx;
            const int x1 = min(x0 + 1, WP - 1);
            const float wx = fx - x0;
            float v00 = bf2f(r0[x0]), v01 = bf2f(r0[x1]);
            float v10 = bf2f(r1[x0]), v11 = bf2f(r1[x1]);
            float a = v00 + (v01 - v00) * wx;
            float c = v10 + (v11 - v10) * wx;
            po[j] = fmaxf(a + (c - a) * wy, 0.f);
        }
        *reinterpret_cast<float4*>(out + (size_t)idx * 4) = o4;
    }
}

extern "C" void kernel_launch(void* const* d_in, const int* in_sizes, int n_in,
                              void* d_out, int out_size, void* d_ws, size_t ws_size,
                              hipStream_t stream) {
    const float* x  = (const float*)d_in[0];
    const float* Wk = (const float*)d_in[1];
    const float* kg = (const float*)d_in[2];
    const float* kb = (const float*)d_in[3];
    const float* km = (const float*)d_in[4];
    const float* kvv= (const float*)d_in[5];
    const float* Wv = (const float*)d_in[6];
    const float* bv = (const float*)d_in[7];
    const float* Ww = (const float*)d_in[8];
    const float* bw = (const float*)d_in[9];
    const float* Wr = (const float*)d_in[10];
    const float* rg = (const float*)d_in[11];
    const float* rb = (const float*)d_in[12];
    const float* rm = (const float*)d_in[13];
    const float* rv = (const float*)d_in[14];

    char* wsb = (char*)d_ws;
    ushort* xpT  = (ushort*)(wsb + BOFF_XPT);
    ushort* qkT  = (ushort*)(wsb + BOFF_QKT);
    ushort* valp = (ushort*)(wsb + BOFF_VAL);
    ushort* ctxT = (ushort*)(wsb + BOFF_CTX);
    ushort* W2   = (ushort*)(wsb + BOFF_W2);
    ushort* Wfb  = (ushort*)(wsb + BOFF_WF);
    float*  bfb  = (float*)(wsb + BOFF_BF);
    ushort* part = (ushort*)(wsb + BOFF_PRT);
    float*  pm   = (float*)(wsb + BOFF_PM);
    float*  pl   = (float*)(wsb + BOFF_PL);
    ushort* Z    = (ushort*)(wsb + BOFF_XPT);  // overlays xpT (dead after qkv)
    float*  out  = (float*)d_out;

    pool_t_kernel<<<8 * 48 * 8, 192, 0, stream>>>(x, xpT);
    prep_kernel<<<1026, 256, 0, stream>>>(Wk, Wv, Wr, Ww, bw, W2, Wfb, bfb);
    qkv_mfma<<<2304, 256, 0, stream>>>(W2, xpT, kg, kb, km, kvv, bv, qkT, valp);
    attn_mfma<<<1152, 256, 0, stream>>>(qkT, valp, part, pm, pl);
    merge_kernel<<<(B_ * N_) / 8, 256, 0, stream>>>(part, pm, pl, ctxT);
    out_mfma<<<2304, 256, 0, stream>>>(Wfb, bfb, rg, rb, rm, rv, ctxT, Z);
    upsample_kernel<<<4096, 256, 0, stream>>>(Z, out);
}